// Round 2
// baseline (670.867 us; speedup 1.0000x reference)
//
#include <hip/hip_runtime.h>
#include <hip/hip_bf16.h>

typedef __attribute__((ext_vector_type(8))) short short8;
typedef __attribute__((ext_vector_type(4))) float f32x4;

// 1/sqrt(64) * log2(e): fold softmax base-2 conversion into Q scale
#define QSCALE 0.1803368801111204f

__device__ inline unsigned short f2b(float f){
  union { float f; unsigned int u; } a; a.f = f;
  unsigned int u = a.u;
  unsigned int r = (u + 0x7fff + ((u >> 16) & 1)) >> 16;
  return (unsigned short)r;
}

// ---------------- cast x -> bf16 ----------------
__global__ void k_cast_x(const float* __restrict__ x, unsigned short* __restrict__ xb, int n4){
  int i = blockIdx.x * blockDim.x + threadIdx.x;
  if (i < n4){
    float4 v = ((const float4*)x)[i];
    ushort4 o;
    o.x = f2b(v.x); o.y = f2b(v.y); o.z = f2b(v.z); o.w = f2b(v.w);
    ((ushort4*)xb)[i] = o;
  }
}

// ---------------- transpose + cast: in[R][Cc] f32 -> out[Cc][R] bf16 ----------------
__global__ void k_transpose_cast(const float* __restrict__ in, unsigned short* __restrict__ out,
                                 int R, int Cc){
  __shared__ float tile[32][33];
  int bx = blockIdx.x, by = blockIdx.y;
  int tx = threadIdx.x, ty = threadIdx.y;
  int col = bx*32 + tx;
  #pragma unroll
  for (int jj = 0; jj < 4; ++jj){
    int row = by*32 + ty + jj*8;
    tile[ty + jj*8][tx] = in[(size_t)row*Cc + col];
  }
  __syncthreads();
  int r = by*32 + tx;
  #pragma unroll
  for (int jj = 0; jj < 4; ++jj){
    int c = bx*32 + ty + jj*8;
    out[(size_t)c*R + r] = f2b(tile[tx][ty + jj*8]);
  }
}

// ---------------- GEMM: C = A[M][K] * Bt[N][K]^T + bias ----------------
// MODE 0: scatter to q/k bf16 buffers [B,H,T,hd] (Q scaled by QSCALE) and
//         V TRANSPOSED to [B,H,hd,T] so attention's PV B-fragments are
//         k-contiguous direct global loads.
// MODE 1: fp32 output [M][N]
template<int MODE>
__global__ __launch_bounds__(256) void k_gemm_bt(
    const unsigned short* __restrict__ A,
    const unsigned short* __restrict__ Bt,
    const float* __restrict__ bias,
    float* __restrict__ Cout,
    unsigned short* __restrict__ qb,
    unsigned short* __restrict__ kbf,
    unsigned short* __restrict__ vbf,
    int Mdim, int Ndim, int Kdim)
{
  __shared__ alignas(16) unsigned short As[128*40];
  __shared__ alignas(16) unsigned short Bs[128*40];
  const int tid  = threadIdx.x;
  const int lane = tid & 63;
  const int wid  = tid >> 6;
  const int wm   = wid >> 1, wn = wid & 1;
  const int bn   = blockIdx.x, bm = blockIdx.y;
  const int l15  = lane & 15, lhi = lane >> 4;

  f32x4 acc[4][4] = {};

  const int rowA0 = bm * 128, rowB0 = bn * 128;
  const int r0  = tid >> 2;          // 0..63
  const int kc0 = (tid & 3) * 8;     // 0,8,16,24

  const int nK = Kdim >> 5;
  for (int kt = 0; kt < nK; ++kt){
    const int kofs = kt*32 + kc0;
    short8 a0 = *(const short8*)(A  + (size_t)(rowA0 + r0)      * Kdim + kofs);
    short8 a1 = *(const short8*)(A  + (size_t)(rowA0 + r0 + 64) * Kdim + kofs);
    short8 b0 = *(const short8*)(Bt + (size_t)(rowB0 + r0)      * Kdim + kofs);
    short8 b1 = *(const short8*)(Bt + (size_t)(rowB0 + r0 + 64) * Kdim + kofs);
    __syncthreads();
    *(short8*)(As + (r0)    *40 + kc0) = a0;
    *(short8*)(As + (r0+64) *40 + kc0) = a1;
    *(short8*)(Bs + (r0)    *40 + kc0) = b0;
    *(short8*)(Bs + (r0+64) *40 + kc0) = b1;
    __syncthreads();
    short8 af[4], bfr[4];
    #pragma unroll
    for (int f = 0; f < 4; ++f){
      af[f]  = *(const short8*)(As + (wm*64 + f*16 + l15)*40 + lhi*8);
      bfr[f] = *(const short8*)(Bs + (wn*64 + f*16 + l15)*40 + lhi*8);
    }
    #pragma unroll
    for (int fm = 0; fm < 4; ++fm)
      #pragma unroll
      for (int fn = 0; fn < 4; ++fn)
        acc[fm][fn] = __builtin_amdgcn_mfma_f32_16x16x32_bf16(af[fm], bfr[fn], acc[fm][fn], 0, 0, 0);
  }

  #pragma unroll
  for (int fm = 0; fm < 4; ++fm){
    #pragma unroll
    for (int fn = 0; fn < 4; ++fn){
      #pragma unroll
      for (int j = 0; j < 4; ++j){
        int m = bm*128 + wm*64 + fm*16 + lhi*4 + j;
        int n = bn*128 + wn*64 + fn*16 + l15;
        float v = acc[fm][fn][j] + bias[n];
        if (MODE == 0){
          int which = n >> 10; int cc2 = n & 1023; int h = cc2 >> 6; int d = cc2 & 63;
          int bb = m >> 11;    int t = m & 2047;
          if (which == 2){
            // V transposed: [B*H][64][2048]
            vbf[((size_t)(bb*16 + h)*64 + d)*2048 + t] = f2b(v);
          } else {
            if (which == 0) v *= QSCALE;   // fold 1/sqrt(64)*log2(e) into Q
            unsigned short* dst = (which == 0) ? qb : kbf;
            dst[(size_t)((bb*16 + h)*2048 + t)*64 + d] = f2b(v);
          }
        } else {
          Cout[(size_t)m * Ndim + n] = v;
        }
      }
    }
  }
}

// ---------------- causal flash attention (barrier-free) ----------------
// grid: (T/64, B*H), block 256 = 4 INDEPENDENT waves x 16 q-rows each.
// qt reversed so longest blocks dispatch first (causal tail fix).
// V is pre-transposed [bh][d][t] -> PV B-frags load straight from global (L2).
__global__ __launch_bounds__(256) void k_attn(
    const unsigned short* __restrict__ qb,
    const unsigned short* __restrict__ kbuf,
    const unsigned short* __restrict__ vT,
    unsigned short* __restrict__ ao)
{
  __shared__ alignas(16) unsigned short P_lds[4*16*72];  // per-wave private regions
  const int tid  = threadIdx.x;
  const int lane = tid & 63, wid = tid >> 6;
  const int l15  = lane & 15, lhi = lane >> 4;
  const int qt   = (int)gridDim.x - 1 - (int)blockIdx.x;  // longest first
  const int bh   = blockIdx.y;
  const int q0w  = qt*64 + wid*16;
  const size_t base = (size_t)bh * 2048 * 64;

  short8 qf[2];
  #pragma unroll
  for (int i = 0; i < 2; ++i)
    qf[i] = *(const short8*)(qb + base + (size_t)(q0w + l15)*64 + i*32 + lhi*8);

  float m_run[4] = {-1e30f, -1e30f, -1e30f, -1e30f};
  float l_run[4] = {0.f, 0.f, 0.f, 0.f};
  f32x4 o_acc[4] = {};

  unsigned short* Pw = P_lds + wid*16*72;   // wave-private, no barriers needed

  const int nkt = qt + 1;
  for (int kt = 0; kt < nkt; ++kt){
    const int kb0 = kt*64;
    // ---- S = Q K^T (Q pre-scaled by 1/8*log2e; S is in log2 units) ----
    f32x4 s[4] = {};
    #pragma unroll
    for (int fn = 0; fn < 4; ++fn){
      #pragma unroll
      for (int i = 0; i < 2; ++i){
        short8 kf = *(const short8*)(kbuf + base + (size_t)(kb0 + fn*16 + l15)*64 + i*32 + lhi*8);
        s[fn] = __builtin_amdgcn_mfma_f32_16x16x32_bf16(qf[i], kf, s[fn], 0, 0, 0);
      }
    }
    // ---- causal mask: only the diagonal tile needs it ----
    if (kt == qt){
      #pragma unroll
      for (int fn = 0; fn < 4; ++fn){
        #pragma unroll
        for (int j = 0; j < 4; ++j){
          int qi = q0w + lhi*4 + j;
          int ki = kb0 + fn*16 + l15;
          if (ki > qi) s[fn][j] = -1e30f;
        }
      }
    }
    // ---- online softmax (per q-row = 16-lane group reduce), base 2 ----
    float p[4][4];
    #pragma unroll
    for (int j = 0; j < 4; ++j){
      float v = fmaxf(fmaxf(s[0][j], s[1][j]), fmaxf(s[2][j], s[3][j]));
      v = fmaxf(v, __shfl_xor(v, 1));
      v = fmaxf(v, __shfl_xor(v, 2));
      v = fmaxf(v, __shfl_xor(v, 4));
      v = fmaxf(v, __shfl_xor(v, 8));
      float mn = fmaxf(m_run[j], v);
      float corr = exp2f(m_run[j] - mn);
      m_run[j] = mn;
      float r = 0.f;
      #pragma unroll
      for (int fn = 0; fn < 4; ++fn){
        float e = exp2f(s[fn][j] - mn);
        p[fn][j] = e;
        r += e;
      }
      r += __shfl_xor(r, 1); r += __shfl_xor(r, 2);
      r += __shfl_xor(r, 4); r += __shfl_xor(r, 8);
      l_run[j] = l_run[j]*corr + r;
      #pragma unroll
      for (int df = 0; df < 4; ++df) o_acc[df][j] *= corr;
    }
    // ---- P (bf16) through wave-private LDS to reach A-frag layout ----
    #pragma unroll
    for (int fn = 0; fn < 4; ++fn)
      #pragma unroll
      for (int j = 0; j < 4; ++j)
        Pw[(lhi*4 + j)*72 + fn*16 + l15] = f2b(p[fn][j]);
    short8 pa[2];
    #pragma unroll
    for (int i = 0; i < 2; ++i)
      pa[i] = *(const short8*)(Pw + l15*72 + i*32 + lhi*8);
    // ---- O += P V  (V^T fragments straight from global/L2) ----
    #pragma unroll
    for (int df = 0; df < 4; ++df){
      #pragma unroll
      for (int i = 0; i < 2; ++i){
        short8 vf = *(const short8*)(vT + base + (size_t)(df*16 + l15)*2048 + kb0 + i*32 + lhi*8);
        o_acc[df] = __builtin_amdgcn_mfma_f32_16x16x32_bf16(pa[i], vf, o_acc[df], 0, 0, 0);
      }
    }
  }
  // ---- normalize + write [B,T,H*hd] bf16 ----
  const int b = bh >> 4, h = bh & 15;
  float rl[4];
  #pragma unroll
  for (int j = 0; j < 4; ++j) rl[j] = 1.0f / l_run[j];
  #pragma unroll
  for (int df = 0; df < 4; ++df){
    #pragma unroll
    for (int j = 0; j < 4; ++j){
      int qrow = q0w + lhi*4 + j;
      float v = o_acc[df][j] * rl[j];
      ao[(size_t)(b*2048 + qrow)*1024 + h*64 + df*16 + l15] = f2b(v);
    }
  }
}

extern "C" void kernel_launch(void* const* d_in, const int* in_sizes, int n_in,
                              void* d_out, int out_size, void* d_ws, size_t ws_size,
                              hipStream_t stream){
  const float* x     = (const float*)d_in[0];
  const float* Wqkv  = (const float*)d_in[1];
  const float* bqkv  = (const float*)d_in[2];
  const float* Wproj = (const float*)d_in[3];
  const float* bproj = (const float*)d_in[4];
  float* out = (float*)d_out;

  unsigned short* ws     = (unsigned short*)d_ws;
  unsigned short* xb     = ws;                       // 8192*1024
  unsigned short* wqkvT  = xb + 8388608;             // 3072*1024
  unsigned short* wprojT = wqkvT + 3145728;          // 1024*1024
  unsigned short* qbuf   = wprojT + 1048576;         // [B,H,T,64]
  unsigned short* kbuf   = qbuf + 8388608;
  unsigned short* vbuf   = kbuf + 8388608;           // [B,H,64,T] (transposed)
  unsigned short* ao     = vbuf + 8388608;           // [B,T,1024]

  k_cast_x<<<8192, 256, 0, stream>>>(x, xb, 2097152);
  k_transpose_cast<<<dim3(96, 32), dim3(32, 8), 0, stream>>>(Wqkv, wqkvT, 1024, 3072);
  k_transpose_cast<<<dim3(32, 32), dim3(32, 8), 0, stream>>>(Wproj, wprojT, 1024, 1024);
  k_gemm_bt<0><<<dim3(24, 64), 256, 0, stream>>>(xb, wqkvT, bqkv, nullptr,
                                                 qbuf, kbuf, vbuf, 8192, 3072, 1024);
  k_attn<<<dim3(32, 64), 256, 0, stream>>>(qbuf, kbuf, vbuf, ao);
  k_gemm_bt<1><<<dim3(8, 64), 256, 0, stream>>>(ao, wprojT, bproj, out,
                                                nullptr, nullptr, nullptr, 8192, 1024, 1024);
}

// Round 3
// 401.311 us; speedup vs baseline: 1.6717x; 1.6717x over previous
//
#include <hip/hip_runtime.h>
#include <hip/hip_bf16.h>

typedef __attribute__((ext_vector_type(8))) short short8;
typedef __attribute__((ext_vector_type(4))) float f32x4;

// 1/sqrt(64) * log2(e): fold softmax base-2 conversion into Q scale
#define QSCALE 0.1803368801111204f

__device__ inline unsigned short f2b(float f){
  union { float f; unsigned int u; } a; a.f = f;
  unsigned int u = a.u;
  unsigned int r = (u + 0x7fff + ((u >> 16) & 1)) >> 16;
  return (unsigned short)r;
}

// ---------------- cast x -> bf16 ----------------
__global__ void k_cast_x(const float* __restrict__ x, unsigned short* __restrict__ xb, int n4){
  int i = blockIdx.x * blockDim.x + threadIdx.x;
  if (i < n4){
    float4 v = ((const float4*)x)[i];
    ushort4 o;
    o.x = f2b(v.x); o.y = f2b(v.y); o.z = f2b(v.z); o.w = f2b(v.w);
    ((ushort4*)xb)[i] = o;
  }
}

// ---------------- transpose + cast: in[R][Cc] f32 -> out[Cc][R] bf16 ----------------
__global__ void k_transpose_cast(const float* __restrict__ in, unsigned short* __restrict__ out,
                                 int R, int Cc){
  __shared__ float tile[32][33];
  int bx = blockIdx.x, by = blockIdx.y;
  int tx = threadIdx.x, ty = threadIdx.y;
  int col = bx*32 + tx;
  #pragma unroll
  for (int jj = 0; jj < 4; ++jj){
    int row = by*32 + ty + jj*8;
    tile[ty + jj*8][tx] = in[(size_t)row*Cc + col];
  }
  __syncthreads();
  int r = by*32 + tx;
  #pragma unroll
  for (int jj = 0; jj < 4; ++jj){
    int c = bx*32 + ty + jj*8;
    out[(size_t)c*R + r] = f2b(tile[tx][ty + jj*8]);
  }
}

// ---------------- GEMM: C = A[M][K] * Bt[N][K]^T + bias ----------------
// MODE 0: scatter to q/k bf16 buffers [B,H,T,hd] (Q scaled by QSCALE) and
//         V TRANSPOSED to [B,H,hd,T].
// MODE 1: fp32 output [M][N]
template<int MODE>
__global__ __launch_bounds__(256) void k_gemm_bt(
    const unsigned short* __restrict__ A,
    const unsigned short* __restrict__ Bt,
    const float* __restrict__ bias,
    float* __restrict__ Cout,
    unsigned short* __restrict__ qb,
    unsigned short* __restrict__ kbf,
    unsigned short* __restrict__ vbf,
    int Mdim, int Ndim, int Kdim)
{
  __shared__ alignas(16) unsigned short As[128*40];
  __shared__ alignas(16) unsigned short Bs[128*40];
  const int tid  = threadIdx.x;
  const int lane = tid & 63;
  const int wid  = tid >> 6;
  const int wm   = wid >> 1, wn = wid & 1;
  const int bn   = blockIdx.x, bm = blockIdx.y;
  const int l15  = lane & 15, lhi = lane >> 4;

  f32x4 acc[4][4] = {};

  const int rowA0 = bm * 128, rowB0 = bn * 128;
  const int r0  = tid >> 2;          // 0..63
  const int kc0 = (tid & 3) * 8;     // 0,8,16,24

  const int nK = Kdim >> 5;
  for (int kt = 0; kt < nK; ++kt){
    const int kofs = kt*32 + kc0;
    short8 a0 = *(const short8*)(A  + (size_t)(rowA0 + r0)      * Kdim + kofs);
    short8 a1 = *(const short8*)(A  + (size_t)(rowA0 + r0 + 64) * Kdim + kofs);
    short8 b0 = *(const short8*)(Bt + (size_t)(rowB0 + r0)      * Kdim + kofs);
    short8 b1 = *(const short8*)(Bt + (size_t)(rowB0 + r0 + 64) * Kdim + kofs);
    __syncthreads();
    *(short8*)(As + (r0)    *40 + kc0) = a0;
    *(short8*)(As + (r0+64) *40 + kc0) = a1;
    *(short8*)(Bs + (r0)    *40 + kc0) = b0;
    *(short8*)(Bs + (r0+64) *40 + kc0) = b1;
    __syncthreads();
    short8 af[4], bfr[4];
    #pragma unroll
    for (int f = 0; f < 4; ++f){
      af[f]  = *(const short8*)(As + (wm*64 + f*16 + l15)*40 + lhi*8);
      bfr[f] = *(const short8*)(Bs + (wn*64 + f*16 + l15)*40 + lhi*8);
    }
    #pragma unroll
    for (int fm = 0; fm < 4; ++fm)
      #pragma unroll
      for (int fn = 0; fn < 4; ++fn)
        acc[fm][fn] = __builtin_amdgcn_mfma_f32_16x16x32_bf16(af[fm], bfr[fn], acc[fm][fn], 0, 0, 0);
  }

  #pragma unroll
  for (int fm = 0; fm < 4; ++fm){
    #pragma unroll
    for (int fn = 0; fn < 4; ++fn){
      #pragma unroll
      for (int j = 0; j < 4; ++j){
        int m = bm*128 + wm*64 + fm*16 + lhi*4 + j;
        int n = bn*128 + wn*64 + fn*16 + l15;
        float v = acc[fm][fn][j] + bias[n];
        if (MODE == 0){
          int which = n >> 10; int cc2 = n & 1023; int h = cc2 >> 6; int d = cc2 & 63;
          int bb = m >> 11;    int t = m & 2047;
          if (which == 2){
            // V transposed: [B*H][64][2048]
            vbf[((size_t)(bb*16 + h)*64 + d)*2048 + t] = f2b(v);
          } else {
            if (which == 0) v *= QSCALE;   // fold 1/sqrt(64)*log2(e) into Q
            unsigned short* dst = (which == 0) ? qb : kbf;
            dst[(size_t)((bb*16 + h)*2048 + t)*64 + d] = f2b(v);
          }
        } else {
          Cout[(size_t)m * Ndim + n] = v;
        }
      }
    }
  }
}

// ---------------- causal flash attention ----------------
// grid (T/64, B*H), block 256 = 4 waves x 16 q-rows. qt descending (LPT).
// Cooperative double-buffered K/V LDS staging (1 barrier/iter, issue-early),
// XOR-swizzled tiles (16B chunk ^= row&7), swapped QK^T -> in-lane softmax.
__global__ __launch_bounds__(256) void k_attn(
    const unsigned short* __restrict__ qb,
    const unsigned short* __restrict__ kbuf,
    const unsigned short* __restrict__ vT,
    unsigned short* __restrict__ ao)
{
  __shared__ alignas(16) unsigned short K_lds[2*64*64];
  __shared__ alignas(16) unsigned short V_lds[2*64*64];
  __shared__ alignas(16) unsigned short P_lds[4*16*72];
  const int tid  = threadIdx.x;
  const int lane = tid & 63, wid = tid >> 6;
  const int l15  = lane & 15, lhi = lane >> 4;
  const int qt   = (int)gridDim.x - 1 - (int)blockIdx.x;  // longest first (LPT)
  const int bh   = blockIdx.y;
  const int q0w  = qt*64 + wid*16;
  const size_t base = (size_t)bh * 2048 * 64;

  // staging map: thread -> (row sr, 16B chunk sc), rows sr and sr+32
  const int sc   = tid & 7;
  const int sr   = tid >> 3;              // 0..31
  const int swz0 = ((sc ^ (sr & 7)) << 3);  // swizzled chunk offset in shorts

  short8 qf[2];
  #pragma unroll
  for (int i = 0; i < 2; ++i)
    qf[i] = *(const short8*)(qb + base + (size_t)(q0w + l15)*64 + i*32 + lhi*8);

  float m_run = -1e30f, l_run = 0.f;
  f32x4 o_acc[4] = {};
  unsigned short* Pw = P_lds + wid*16*72;
  const int nkt = qt + 1;

  // prologue: stage tile 0 into buffer 0
  {
    short8 k0 = *(const short8*)(kbuf + base + (size_t)(sr     )*64 + sc*8);
    short8 k1 = *(const short8*)(kbuf + base + (size_t)(sr + 32)*64 + sc*8);
    short8 v0 = *(const short8*)(vT   + base + (size_t)(sr     )*2048 + sc*8);
    short8 v1 = *(const short8*)(vT   + base + (size_t)(sr + 32)*2048 + sc*8);
    *(short8*)(K_lds + (sr     )*64 + swz0) = k0;
    *(short8*)(K_lds + (sr + 32)*64 + swz0) = k1;
    *(short8*)(V_lds + (sr     )*64 + swz0) = v0;
    *(short8*)(V_lds + (sr + 32)*64 + swz0) = v1;
  }
  __syncthreads();

  for (int kt = 0; kt < nkt; ++kt){
    const int cur = kt & 1;
    const unsigned short* Kc = K_lds + cur*4096;
    const unsigned short* Vc = V_lds + cur*4096;
    const bool pre = (kt + 1 < nkt);
    short8 pk0, pk1, pv0, pv1;
    if (pre){                       // issue next-tile loads early (T14)
      const int kb = (kt+1)*64;
      pk0 = *(const short8*)(kbuf + base + (size_t)(kb + sr     )*64 + sc*8);
      pk1 = *(const short8*)(kbuf + base + (size_t)(kb + sr + 32)*64 + sc*8);
      pv0 = *(const short8*)(vT   + base + (size_t)(sr     )*2048 + kb + sc*8);
      pv1 = *(const short8*)(vT   + base + (size_t)(sr + 32)*2048 + kb + sc*8);
    }

    // ---- S^T = K Q^T : row=k (lhi*4+j), col=q (l15) ----
    f32x4 s[4] = {};
    #pragma unroll
    for (int fn = 0; fn < 4; ++fn){
      #pragma unroll
      for (int i = 0; i < 2; ++i){
        short8 kf = *(const short8*)(Kc + (fn*16 + l15)*64 + (((i*4 + lhi) ^ (l15 & 7)) << 3));
        s[fn] = __builtin_amdgcn_mfma_f32_16x16x32_bf16(kf, qf[i], s[fn], 0, 0, 0);
      }
    }
    // ---- causal mask (diagonal tile only): k-in-tile > q-in-block ----
    if (kt == qt){
      const int qi = wid*16 + l15;
      #pragma unroll
      for (int fn = 0; fn < 4; ++fn){
        #pragma unroll
        for (int j = 0; j < 4; ++j){
          int ki = fn*16 + lhi*4 + j;
          if (ki > qi) s[fn][j] = -1e30f;
        }
      }
    }
    // ---- online softmax: in-lane over 16 + 2 shfl (q = l15) ----
    float t0 = fmaxf(fmaxf(s[0][0], s[0][1]), fmaxf(s[0][2], s[0][3]));
    float t1 = fmaxf(fmaxf(s[1][0], s[1][1]), fmaxf(s[1][2], s[1][3]));
    float t2 = fmaxf(fmaxf(s[2][0], s[2][1]), fmaxf(s[2][2], s[2][3]));
    float t3 = fmaxf(fmaxf(s[3][0], s[3][1]), fmaxf(s[3][2], s[3][3]));
    float rmax = fmaxf(fmaxf(t0, t1), fmaxf(t2, t3));
    rmax = fmaxf(rmax, __shfl_xor(rmax, 16));
    rmax = fmaxf(rmax, __shfl_xor(rmax, 32));
    float mn   = fmaxf(m_run, rmax);
    float corr = exp2f(m_run - mn);
    m_run = mn;
    float rsum = 0.f;
    unsigned long long pw[4];
    #pragma unroll
    for (int fn = 0; fn < 4; ++fn){
      float e0 = exp2f(s[fn][0] - mn);
      float e1 = exp2f(s[fn][1] - mn);
      float e2 = exp2f(s[fn][2] - mn);
      float e3 = exp2f(s[fn][3] - mn);
      rsum += (e0 + e1) + (e2 + e3);
      pw[fn] = (unsigned long long)f2b(e0)        | ((unsigned long long)f2b(e1) << 16)
             | ((unsigned long long)f2b(e2) << 32) | ((unsigned long long)f2b(e3) << 48);
    }
    rsum += __shfl_xor(rsum, 16);
    rsum += __shfl_xor(rsum, 32);
    l_run = l_run * corr + rsum;
    // broadcast corr from q=l15 lanes to o_acc rows q=lhi*4+j
    float cj[4];
    #pragma unroll
    for (int j = 0; j < 4; ++j) cj[j] = __shfl(corr, (lane & 48) | (lhi*4 + j));
    #pragma unroll
    for (int df = 0; df < 4; ++df)
      #pragma unroll
      for (int j = 0; j < 4; ++j) o_acc[df][j] *= cj[j];
    // ---- P^T -> wave-private LDS as [q][k] (b64 packed), read back as A-frag ----
    #pragma unroll
    for (int fn = 0; fn < 4; ++fn)
      *(unsigned long long*)(Pw + l15*72 + fn*16 + lhi*4) = pw[fn];
    short8 pa[2];
    #pragma unroll
    for (int i = 0; i < 2; ++i)
      pa[i] = *(const short8*)(Pw + l15*72 + i*32 + lhi*8);
    // ---- O += P V ----
    #pragma unroll
    for (int df = 0; df < 4; ++df){
      #pragma unroll
      for (int i = 0; i < 2; ++i){
        short8 vf = *(const short8*)(Vc + (df*16 + l15)*64 + (((i*4 + lhi) ^ (l15 & 7)) << 3));
        o_acc[df] = __builtin_amdgcn_mfma_f32_16x16x32_bf16(pa[i], vf, o_acc[df], 0, 0, 0);
      }
    }
    // ---- write staged next tile into other buffer ----
    if (pre){
      unsigned short* K = K_lds + (cur ^ 1)*4096;
      unsigned short* V = V_lds + (cur ^ 1)*4096;
      *(short8*)(K + (sr     )*64 + swz0) = pk0;
      *(short8*)(K + (sr + 32)*64 + swz0) = pk1;
      *(short8*)(V + (sr     )*64 + swz0) = pv0;
      *(short8*)(V + (sr + 32)*64 + swz0) = pv1;
    }
    __syncthreads();
  }
  // ---- normalize + write [B,T,H*hd] bf16 ----
  const int b = bh >> 4, h = bh & 15;
  float rln = 1.0f / l_run;
  #pragma unroll
  for (int j = 0; j < 4; ++j){
    float rl = __shfl(rln, (lane & 48) | (lhi*4 + j));
    int qrow = q0w + lhi*4 + j;
    #pragma unroll
    for (int df = 0; df < 4; ++df){
      float v = o_acc[df][j] * rl;
      ao[(size_t)(b*2048 + qrow)*1024 + h*64 + df*16 + l15] = f2b(v);
    }
  }
}

extern "C" void kernel_launch(void* const* d_in, const int* in_sizes, int n_in,
                              void* d_out, int out_size, void* d_ws, size_t ws_size,
                              hipStream_t stream){
  const float* x     = (const float*)d_in[0];
  const float* Wqkv  = (const float*)d_in[1];
  const float* bqkv  = (const float*)d_in[2];
  const float* Wproj = (const float*)d_in[3];
  const float* bproj = (const float*)d_in[4];
  float* out = (float*)d_out;

  unsigned short* ws     = (unsigned short*)d_ws;
  unsigned short* xb     = ws;                       // 8192*1024
  unsigned short* wqkvT  = xb + 8388608;             // 3072*1024
  unsigned short* wprojT = wqkvT + 3145728;          // 1024*1024
  unsigned short* qbuf   = wprojT + 1048576;         // [B,H,T,64]
  unsigned short* kbuf   = qbuf + 8388608;
  unsigned short* vbuf   = kbuf + 8388608;           // [B,H,64,T] (transposed)
  unsigned short* ao     = vbuf + 8388608;           // [B,T,1024]

  k_cast_x<<<8192, 256, 0, stream>>>(x, xb, 2097152);
  k_transpose_cast<<<dim3(96, 32), dim3(32, 8), 0, stream>>>(Wqkv, wqkvT, 1024, 3072);
  k_transpose_cast<<<dim3(32, 32), dim3(32, 8), 0, stream>>>(Wproj, wprojT, 1024, 1024);
  k_gemm_bt<0><<<dim3(24, 64), 256, 0, stream>>>(xb, wqkvT, bqkv, nullptr,
                                                 qbuf, kbuf, vbuf, 8192, 3072, 1024);
  k_attn<<<dim3(32, 64), 256, 0, stream>>>(qbuf, kbuf, vbuf, ao);
  k_gemm_bt<1><<<dim3(8, 64), 256, 0, stream>>>(ao, wprojT, bproj, out,
                                                nullptr, nullptr, nullptr, 8192, 1024, 1024);
}

// Round 4
// 388.457 us; speedup vs baseline: 1.7270x; 1.0331x over previous
//
#include <hip/hip_runtime.h>
#include <hip/hip_bf16.h>

typedef __attribute__((ext_vector_type(8))) short short8;
typedef __attribute__((ext_vector_type(4))) float f32x4;

// 1/sqrt(64) * log2(e): fold softmax base-2 conversion into Q scale
#define QSCALE 0.1803368801111204f

__device__ inline unsigned short f2b(float f){
  union { float f; unsigned int u; } a; a.f = f;
  unsigned int u = a.u;
  unsigned int r = (u + 0x7fff + ((u >> 16) & 1)) >> 16;
  return (unsigned short)r;
}

// RNE float->bf16 via HIP intrinsic: compiler can fuse pairs into v_cvt_pk_bf16_f32
__device__ inline unsigned short f2brn(float f){
  __hip_bfloat16 h = __float2bfloat16(f);
  union { __hip_bfloat16 h; unsigned short u; } c; c.h = h;
  return c.u;
}

// async global->LDS, 16B per lane (wave-uniform LDS base + lane*16)
__device__ inline void gload16(const unsigned short* g, unsigned short* l){
  __builtin_amdgcn_global_load_lds((const __attribute__((address_space(1))) void*)g,
                                   (__attribute__((address_space(3))) void*)l, 16, 0, 0);
}

// ---------------- cast x -> bf16 ----------------
__global__ void k_cast_x(const float* __restrict__ x, unsigned short* __restrict__ xb, int n4){
  int i = blockIdx.x * blockDim.x + threadIdx.x;
  if (i < n4){
    float4 v = ((const float4*)x)[i];
    ushort4 o;
    o.x = f2b(v.x); o.y = f2b(v.y); o.z = f2b(v.z); o.w = f2b(v.w);
    ((ushort4*)xb)[i] = o;
  }
}

// ---------------- transpose + cast: in[R][Cc] f32 -> out[Cc][R] bf16 ----------------
__global__ void k_transpose_cast(const float* __restrict__ in, unsigned short* __restrict__ out,
                                 int R, int Cc){
  __shared__ float tile[32][33];
  int bx = blockIdx.x, by = blockIdx.y;
  int tx = threadIdx.x, ty = threadIdx.y;
  int col = bx*32 + tx;
  #pragma unroll
  for (int jj = 0; jj < 4; ++jj){
    int row = by*32 + ty + jj*8;
    tile[ty + jj*8][tx] = in[(size_t)row*Cc + col];
  }
  __syncthreads();
  int r = by*32 + tx;
  #pragma unroll
  for (int jj = 0; jj < 4; ++jj){
    int c = bx*32 + ty + jj*8;
    out[(size_t)c*R + r] = f2b(tile[tx][ty + jj*8]);
  }
}

// ---------------- GEMM (m97 structure): C = A[M][K] * Bt[N][K]^T + bias ----------------
// global_load_lds width-16 staging into linear [128][32] LDS tiles, 2 barriers/kt.
// MODE 0: scatter to q/k bf16 buffers [B,H,T,hd] (Q scaled by QSCALE) and V^T [B,H,hd,T].
// MODE 1: fp32 output [M][N]
template<int MODE>
__global__ __launch_bounds__(256) void k_gemm_bt(
    const unsigned short* __restrict__ A,
    const unsigned short* __restrict__ Bt,
    const float* __restrict__ bias,
    float* __restrict__ Cout,
    unsigned short* __restrict__ qb,
    unsigned short* __restrict__ kbf,
    unsigned short* __restrict__ vbf,
    int Mdim, int Ndim, int Kdim)
{
  __shared__ alignas(16) unsigned short As[128*32];
  __shared__ alignas(16) unsigned short Bs[128*32];
  const int tid  = threadIdx.x;
  const int lane = tid & 63;
  const int wid  = tid >> 6;
  const int wm   = wid >> 1, wn = wid & 1;
  const int bn   = blockIdx.x, bm = blockIdx.y;
  const int l15  = lane & 15, lhi = lane >> 4;

  f32x4 acc[4][4] = {};

  const int rowA0 = bm * 128, rowB0 = bn * 128;
  // staging: thread tid -> row tid>>2, 16B chunk tid&3; LDS offset = tid*16B (linear)
  const unsigned short* Ag = A  + (size_t)(rowA0 + (tid>>2)) * Kdim + (tid&3)*8;
  const unsigned short* Bg = Bt + (size_t)(rowB0 + (tid>>2)) * Kdim + (tid&3)*8;
  const size_t row64 = (size_t)64 * Kdim;

  const int nK = Kdim >> 5;
  for (int kt = 0; kt < nK; ++kt){
    const int ko = kt*32;
    gload16(Ag + ko,         As + tid*8);
    gload16(Ag + row64 + ko, As + 2048 + tid*8);
    gload16(Bg + ko,         Bs + tid*8);
    gload16(Bg + row64 + ko, Bs + 2048 + tid*8);
    asm volatile("s_waitcnt vmcnt(0)" ::: "memory");
    __syncthreads();
    short8 af[4], bfr[4];
    #pragma unroll
    for (int f = 0; f < 4; ++f){
      af[f]  = *(const short8*)(As + (wm*64 + f*16 + l15)*32 + lhi*8);
      bfr[f] = *(const short8*)(Bs + (wn*64 + f*16 + l15)*32 + lhi*8);
    }
    #pragma unroll
    for (int fm = 0; fm < 4; ++fm)
      #pragma unroll
      for (int fn = 0; fn < 4; ++fn)
        acc[fm][fn] = __builtin_amdgcn_mfma_f32_16x16x32_bf16(af[fm], bfr[fn], acc[fm][fn], 0, 0, 0);
    __syncthreads();
  }

  #pragma unroll
  for (int fm = 0; fm < 4; ++fm){
    #pragma unroll
    for (int fn = 0; fn < 4; ++fn){
      #pragma unroll
      for (int j = 0; j < 4; ++j){
        int m = bm*128 + wm*64 + fm*16 + lhi*4 + j;
        int n = bn*128 + wn*64 + fn*16 + l15;
        float v = acc[fm][fn][j] + bias[n];
        if (MODE == 0){
          int which = n >> 10; int cc2 = n & 1023; int h = cc2 >> 6; int d = cc2 & 63;
          int bb = m >> 11;    int t = m & 2047;
          if (which == 2){
            vbf[((size_t)(bb*16 + h)*64 + d)*2048 + t] = f2b(v);
          } else {
            if (which == 0) v *= QSCALE;
            unsigned short* dst = (which == 0) ? qb : kbf;
            dst[(size_t)((bb*16 + h)*2048 + t)*64 + d] = f2b(v);
          }
        } else {
          Cout[(size_t)m * Ndim + n] = v;
        }
      }
    }
  }
}

// ---------------- causal flash attention ----------------
// grid (T/128, B*H), block 256 = 4 waves x 32 q-rows (2 column groups of 16).
// K/V double-buffered via global_load_lds with pre-swizzled SOURCE chunks
// (LDS linear dest, XOR-swizzled read). 1 barrier + vmcnt(0) per tile.
// Swapped QK^T -> in-lane softmax; defer-max (THR=8 in log2 units).
__global__ __launch_bounds__(256) void k_attn(
    const unsigned short* __restrict__ qb,
    const unsigned short* __restrict__ kbuf,
    const unsigned short* __restrict__ vT,
    unsigned short* __restrict__ ao)
{
  __shared__ alignas(16) unsigned short K_lds[2*64*64];
  __shared__ alignas(16) unsigned short V_lds[2*64*64];
  __shared__ alignas(16) unsigned short P_lds[4*32*72];
  const int tid  = threadIdx.x;
  const int lane = tid & 63, wid = tid >> 6;
  const int l15  = lane & 15, lhi = lane >> 4;
  const int qt   = (int)gridDim.x - 1 - (int)blockIdx.x;  // longest first (LPT)
  const int bh   = blockIdx.y;
  const size_t base = (size_t)bh * 2048 * 64;
  const int q0w  = qt*128 + wid*32;
  const int qmaxw = q0w + 31;

  // staging: thread -> rows sr, sr+32; source chunk pre-swizzled so that
  // LDS slot (row, cs) holds global chunk cs ^ (row&7)  ((row+32)&7 == row&7)
  const int sr  = tid >> 3;
  const int sck = (tid & 7) ^ (sr & 7);
  const unsigned short* kg0 = kbuf + base + (size_t)(sr     )*64 + sck*8;
  const unsigned short* kg1 = kbuf + base + (size_t)(sr + 32)*64 + sck*8;
  const unsigned short* vg0 = vT   + base + (size_t)(sr     )*2048 + sck*8;
  const unsigned short* vg1 = vT   + base + (size_t)(sr + 32)*2048 + sck*8;

  // Q fragments: 2 column groups x 2 k-chunks
  short8 qf[2][2];
  #pragma unroll
  for (int g = 0; g < 2; ++g)
    #pragma unroll
    for (int i = 0; i < 2; ++i)
      qf[g][i] = *(const short8*)(qb + base + (size_t)(q0w + g*16 + l15)*64 + i*32 + lhi*8);

  float m_run[2] = {-1e30f, -1e30f};
  float l_run[2] = {0.f, 0.f};
  f32x4 o_acc[2][4] = {};
  unsigned short* Pw = P_lds + wid*32*72;

  const int nkt = 2*qt + 2;

  // prologue: stage tile 0 into buffer 0
  gload16(kg0,              K_lds + tid*8);
  gload16(kg1,              K_lds + 2048 + tid*8);
  gload16(vg0,              V_lds + tid*8);
  gload16(vg1,              V_lds + 2048 + tid*8);
  asm volatile("s_waitcnt vmcnt(0)" ::: "memory");
  __syncthreads();

  for (int kt = 0; kt < nkt; ++kt){
    const int cur = kt & 1;
    // issue next-tile staging early (overlaps with compute below)
    if (kt + 1 < nkt){
      const int kb = (kt+1)*64;
      unsigned short* Kd = K_lds + (cur^1)*4096;
      unsigned short* Vd = V_lds + (cur^1)*4096;
      gload16(kg0 + (size_t)kb*64, Kd + tid*8);
      gload16(kg1 + (size_t)kb*64, Kd + 2048 + tid*8);
      gload16(vg0 + kb,            Vd + tid*8);
      gload16(vg1 + kb,            Vd + 2048 + tid*8);
    }
    if (kt*64 <= qmaxw){   // wave-uniform skip of fully-masked diagonal tiles
      const unsigned short* Kc = K_lds + cur*4096;
      const unsigned short* Vc = V_lds + cur*4096;
      // ---- S^T = K Q^T per group: row=k(lhi*4+j within fn*16), col=q(l15) ----
      short8 kf[4][2];
      #pragma unroll
      for (int fn = 0; fn < 4; ++fn)
        #pragma unroll
        for (int i = 0; i < 2; ++i)
          kf[fn][i] = *(const short8*)(Kc + (fn*16 + l15)*64 + (((i*4 + lhi) ^ (l15 & 7)) << 3));
      f32x4 s[2][4] = {};
      __builtin_amdgcn_s_setprio(1);
      #pragma unroll
      for (int g = 0; g < 2; ++g)
        #pragma unroll
        for (int fn = 0; fn < 4; ++fn)
          #pragma unroll
          for (int i = 0; i < 2; ++i)
            s[g][fn] = __builtin_amdgcn_mfma_f32_16x16x32_bf16(kf[fn][i], qf[g][i], s[g][fn], 0, 0, 0);
      __builtin_amdgcn_s_setprio(0);
      // ---- causal mask (diagonal region only) ----
      if (kt >= 2*qt){
        #pragma unroll
        for (int g = 0; g < 2; ++g){
          const int qi = q0w + g*16 + l15;
          #pragma unroll
          for (int fn = 0; fn < 4; ++fn)
            #pragma unroll
            for (int j = 0; j < 4; ++j){
              int ki = kt*64 + fn*16 + lhi*4 + j;
              if (ki > qi) s[g][fn][j] = -1e30f;
            }
        }
      }
      // ---- per-group row max (in-lane 16 + 2 shfl) ----
      float rmax[2];
      #pragma unroll
      for (int g = 0; g < 2; ++g){
        float t0 = fmaxf(fmaxf(s[g][0][0], s[g][0][1]), fmaxf(s[g][0][2], s[g][0][3]));
        float t1 = fmaxf(fmaxf(s[g][1][0], s[g][1][1]), fmaxf(s[g][1][2], s[g][1][3]));
        float t2 = fmaxf(fmaxf(s[g][2][0], s[g][2][1]), fmaxf(s[g][2][2], s[g][2][3]));
        float t3 = fmaxf(fmaxf(s[g][3][0], s[g][3][1]), fmaxf(s[g][3][2], s[g][3][3]));
        float v = fmaxf(fmaxf(t0, t1), fmaxf(t2, t3));
        v = fmaxf(v, __shfl_xor(v, 16));
        v = fmaxf(v, __shfl_xor(v, 32));
        rmax[g] = v;
      }
      // ---- defer-max: rescale only when max grows past THR=8 (log2 units) ----
      bool need = (rmax[0] > m_run[0] + 8.f) || (rmax[1] > m_run[1] + 8.f);
      if (__any(need)){
        #pragma unroll
        for (int g = 0; g < 2; ++g){
          float mn   = fmaxf(m_run[g], rmax[g]);
          float corr = exp2f(m_run[g] - mn);
          m_run[g] = mn;
          l_run[g] *= corr;
          #pragma unroll
          for (int j = 0; j < 4; ++j){
            float cj = __shfl(corr, (lane & 48) | (lhi*4 + j));
            #pragma unroll
            for (int df = 0; df < 4; ++df) o_acc[g][df][j] *= cj;
          }
        }
      }
      // ---- P = exp2(S - m), pack bf16 (cvt_pk), accumulate row sums ----
      #pragma unroll
      for (int g = 0; g < 2; ++g){
        const float mr = m_run[g];
        float rsum = 0.f;
        unsigned long long pwq[4];
        #pragma unroll
        for (int fn = 0; fn < 4; ++fn){
          float e0 = exp2f(s[g][fn][0] - mr);
          float e1 = exp2f(s[g][fn][1] - mr);
          float e2 = exp2f(s[g][fn][2] - mr);
          float e3 = exp2f(s[g][fn][3] - mr);
          rsum += (e0 + e1) + (e2 + e3);
          unsigned int w0 = (unsigned int)f2brn(e0) | ((unsigned int)f2brn(e1) << 16);
          unsigned int w1 = (unsigned int)f2brn(e2) | ((unsigned int)f2brn(e3) << 16);
          pwq[fn] = (unsigned long long)w0 | ((unsigned long long)w1 << 32);
        }
        rsum += __shfl_xor(rsum, 16);
        rsum += __shfl_xor(rsum, 32);
        l_run[g] += rsum;
        #pragma unroll
        for (int fn = 0; fn < 4; ++fn)
          *(unsigned long long*)(Pw + (g*16 + l15)*72 + fn*16 + lhi*4) = pwq[fn];
      }
      // ---- O += P V ----
      short8 pa[2][2];
      #pragma unroll
      for (int g = 0; g < 2; ++g)
        #pragma unroll
        for (int i = 0; i < 2; ++i)
          pa[g][i] = *(const short8*)(Pw + (g*16 + l15)*72 + i*32 + lhi*8);
      __builtin_amdgcn_s_setprio(1);
      #pragma unroll
      for (int df = 0; df < 4; ++df){
        #pragma unroll
        for (int i = 0; i < 2; ++i){
          short8 vf = *(const short8*)(Vc + (df*16 + l15)*64 + (((i*4 + lhi) ^ (l15 & 7)) << 3));
          #pragma unroll
          for (int g = 0; g < 2; ++g)
            o_acc[g][df] = __builtin_amdgcn_mfma_f32_16x16x32_bf16(pa[g][i], vf, o_acc[g][df], 0, 0, 0);
        }
      }
      __builtin_amdgcn_s_setprio(0);
    }
    asm volatile("s_waitcnt vmcnt(0)" ::: "memory");
    __syncthreads();
  }
  // ---- normalize + write [B,T,H*hd] bf16 ----
  const int b = bh >> 4, h = bh & 15;
  #pragma unroll
  for (int g = 0; g < 2; ++g){
    float rln = 1.0f / l_run[g];
    #pragma unroll
    for (int j = 0; j < 4; ++j){
      float rl = __shfl(rln, (lane & 48) | (lhi*4 + j));
      int qrow = q0w + g*16 + lhi*4 + j;
      #pragma unroll
      for (int df = 0; df < 4; ++df){
        float v = o_acc[g][df][j] * rl;
        ao[(size_t)(b*2048 + qrow)*1024 + h*64 + df*16 + l15] = f2brn(v);
      }
    }
  }
}

extern "C" void kernel_launch(void* const* d_in, const int* in_sizes, int n_in,
                              void* d_out, int out_size, void* d_ws, size_t ws_size,
                              hipStream_t stream){
  const float* x     = (const float*)d_in[0];
  const float* Wqkv  = (const float*)d_in[1];
  const float* bqkv  = (const float*)d_in[2];
  const float* Wproj = (const float*)d_in[3];
  const float* bproj = (const float*)d_in[4];
  float* out = (float*)d_out;

  unsigned short* ws     = (unsigned short*)d_ws;
  unsigned short* xb     = ws;                       // 8192*1024
  unsigned short* wqkvT  = xb + 8388608;             // 3072*1024
  unsigned short* wprojT = wqkvT + 3145728;          // 1024*1024
  unsigned short* qbuf   = wprojT + 1048576;         // [B,H,T,64]
  unsigned short* kbuf   = qbuf + 8388608;
  unsigned short* vbuf   = kbuf + 8388608;           // [B,H,64,T] (transposed)
  unsigned short* ao     = vbuf + 8388608;           // [B,T,1024]

  k_cast_x<<<8192, 256, 0, stream>>>(x, xb, 2097152);
  k_transpose_cast<<<dim3(96, 32), dim3(32, 8), 0, stream>>>(Wqkv, wqkvT, 1024, 3072);
  k_transpose_cast<<<dim3(32, 32), dim3(32, 8), 0, stream>>>(Wproj, wprojT, 1024, 1024);
  k_gemm_bt<0><<<dim3(24, 64), 256, 0, stream>>>(xb, wqkvT, bqkv, nullptr,
                                                 qbuf, kbuf, vbuf, 8192, 3072, 1024);
  k_attn<<<dim3(16, 64), 256, 0, stream>>>(qbuf, kbuf, vbuf, ao);
  k_gemm_bt<1><<<dim3(8, 64), 256, 0, stream>>>(ao, wprojT, bproj, out,
                                                nullptr, nullptr, nullptr, 8192, 1024, 1024);
}

// Round 5
// 385.338 us; speedup vs baseline: 1.7410x; 1.0081x over previous
//
#include <hip/hip_runtime.h>
#include <hip/hip_bf16.h>

typedef __attribute__((ext_vector_type(8))) short short8;
typedef __attribute__((ext_vector_type(4))) float f32x4;

// 1/sqrt(64) * log2(e): fold softmax base-2 conversion into Q scale
#define QSCALE 0.1803368801111204f

__device__ inline unsigned short f2b(float f){
  union { float f; unsigned int u; } a; a.f = f;
  unsigned int u = a.u;
  unsigned int r = (u + 0x7fff + ((u >> 16) & 1)) >> 16;
  return (unsigned short)r;
}

// RNE float->bf16 via HIP intrinsic: compiler can fuse pairs into v_cvt_pk_bf16_f32
__device__ inline unsigned short f2brn(float f){
  __hip_bfloat16 h = __float2bfloat16(f);
  union { __hip_bfloat16 h; unsigned short u; } c; c.h = h;
  return c.u;
}

// async global->LDS, 16B per lane (wave-uniform LDS base + lane*16)
__device__ inline void gload16(const unsigned short* g, unsigned short* l){
  __builtin_amdgcn_global_load_lds((const __attribute__((address_space(1))) void*)g,
                                   (__attribute__((address_space(3))) void*)l, 16, 0, 0);
}

// ---------------- cast x -> bf16 ----------------
__global__ void k_cast_x(const float* __restrict__ x, unsigned short* __restrict__ xb, int n4){
  int i = blockIdx.x * blockDim.x + threadIdx.x;
  if (i < n4){
    float4 v = ((const float4*)x)[i];
    ushort4 o;
    o.x = f2b(v.x); o.y = f2b(v.y); o.z = f2b(v.z); o.w = f2b(v.w);
    ((ushort4*)xb)[i] = o;
  }
}

// ---------------- transpose + cast: in[R][Cc] f32 -> out[Cc][R] bf16 ----------------
__global__ void k_transpose_cast(const float* __restrict__ in, unsigned short* __restrict__ out,
                                 int R, int Cc){
  __shared__ float tile[32][33];
  int bx = blockIdx.x, by = blockIdx.y;
  int tx = threadIdx.x, ty = threadIdx.y;
  int col = bx*32 + tx;
  #pragma unroll
  for (int jj = 0; jj < 4; ++jj){
    int row = by*32 + ty + jj*8;
    tile[ty + jj*8][tx] = in[(size_t)row*Cc + col];
  }
  __syncthreads();
  int r = by*32 + tx;
  #pragma unroll
  for (int jj = 0; jj < 4; ++jj){
    int c = bx*32 + ty + jj*8;
    out[(size_t)c*R + r] = f2b(tile[tx][ty + jj*8]);
  }
}

// ---------------- GEMM: C = A[M][K] * Bt[N][K]^T + bias ----------------
// T3/T4 pipeline: 3 LDS buffers, global_load_lds width-16, counted vmcnt(4),
// ONE raw s_barrier per K-step (no vmcnt(0) drain in the loop).
// MODE 0: scatter q/k [B,H,T,hd] (Q scaled) + V^T [B,H,hd,T]. MODE 1: f32 [M][N].
template<int MODE>
__global__ __launch_bounds__(256) void k_gemm_bt(
    const unsigned short* __restrict__ A,
    const unsigned short* __restrict__ Bt,
    const float* __restrict__ bias,
    float* __restrict__ Cout,
    unsigned short* __restrict__ qb,
    unsigned short* __restrict__ kbf,
    unsigned short* __restrict__ vbf,
    int Mdim, int Ndim, int Kdim)
{
  __shared__ alignas(16) unsigned short As[3*128*32];
  __shared__ alignas(16) unsigned short Bs[3*128*32];
  const int tid  = threadIdx.x;
  const int lane = tid & 63;
  const int wid  = tid >> 6;
  const int wm   = wid >> 1, wn = wid & 1;
  const int bn   = blockIdx.x, bm = blockIdx.y;
  const int l15  = lane & 15, lhi = lane >> 4;

  f32x4 acc[4][4] = {};

  const int rowA0 = bm * 128, rowB0 = bn * 128;
  const unsigned short* Ag = A  + (size_t)(rowA0 + (tid>>2)) * Kdim + (tid&3)*8;
  const unsigned short* Bg = Bt + (size_t)(rowB0 + (tid>>2)) * Kdim + (tid&3)*8;
  const size_t row64 = (size_t)64 * Kdim;

  const int nK = Kdim >> 5;

#define G_STAGE(t, b) do {                                   \
    const int _ko = (t)*32;                                  \
    unsigned short* _as = As + (b)*4096;                     \
    unsigned short* _bs = Bs + (b)*4096;                     \
    gload16(Ag + _ko,         _as + tid*8);                  \
    gload16(Ag + row64 + _ko, _as + 2048 + tid*8);           \
    gload16(Bg + _ko,         _bs + tid*8);                  \
    gload16(Bg + row64 + _ko, _bs + 2048 + tid*8);           \
  } while(0)

  // prologue: 2-deep prefetch
  G_STAGE(0, 0);
  G_STAGE(1, 1);

  int cb = 0, sb = 2;
  for (int kt = 0; kt < nK; ++kt){
    asm volatile("s_waitcnt vmcnt(4)" ::: "memory");   // oldest tile's 4 loads done
    __builtin_amdgcn_s_barrier();                      // all waves' loads done
    if (kt + 2 < nK) G_STAGE(kt + 2, sb);
    const unsigned short* Ac = As + cb*4096;
    const unsigned short* Bc = Bs + cb*4096;
    short8 af[4], bfr[4];
    #pragma unroll
    for (int f = 0; f < 4; ++f){
      af[f]  = *(const short8*)(Ac + (wm*64 + f*16 + l15)*32 + lhi*8);
      bfr[f] = *(const short8*)(Bc + (wn*64 + f*16 + l15)*32 + lhi*8);
    }
    __builtin_amdgcn_s_setprio(1);
    #pragma unroll
    for (int fm = 0; fm < 4; ++fm)
      #pragma unroll
      for (int fn = 0; fn < 4; ++fn)
        acc[fm][fn] = __builtin_amdgcn_mfma_f32_16x16x32_bf16(af[fm], bfr[fn], acc[fm][fn], 0, 0, 0);
    __builtin_amdgcn_s_setprio(0);
    cb = (cb == 2) ? 0 : cb + 1;
    sb = (sb == 2) ? 0 : sb + 1;
  }
#undef G_STAGE

  #pragma unroll
  for (int fm = 0; fm < 4; ++fm){
    #pragma unroll
    for (int fn = 0; fn < 4; ++fn){
      #pragma unroll
      for (int j = 0; j < 4; ++j){
        int m = bm*128 + wm*64 + fm*16 + lhi*4 + j;
        int n = bn*128 + wn*64 + fn*16 + l15;
        float v = acc[fm][fn][j] + bias[n];
        if (MODE == 0){
          int which = n >> 10; int cc2 = n & 1023; int h = cc2 >> 6; int d = cc2 & 63;
          int bb = m >> 11;    int t = m & 2047;
          if (which == 2){
            vbf[((size_t)(bb*16 + h)*64 + d)*2048 + t] = f2b(v);
          } else {
            if (which == 0) v *= QSCALE;
            unsigned short* dst = (which == 0) ? qb : kbf;
            dst[(size_t)((bb*16 + h)*2048 + t)*64 + d] = f2b(v);
          }
        } else {
          Cout[(size_t)m * Ndim + n] = v;
        }
      }
    }
  }
}

// ---------------- causal flash attention ----------------
// grid (T/128, B*H), block 256 = 4 waves x 32 q-rows (2 column groups of 16).
// T3/T4 pipeline: 3 K/V LDS buffers, counted vmcnt(4), ONE raw barrier/tile.
// K/V staged via global_load_lds with pre-swizzled SOURCE chunks (linear dest,
// XOR-swizzled read). Swapped QK^T -> in-lane softmax; defer-max THR=8.
__global__ __launch_bounds__(256) void k_attn(
    const unsigned short* __restrict__ qb,
    const unsigned short* __restrict__ kbuf,
    const unsigned short* __restrict__ vT,
    unsigned short* __restrict__ ao)
{
  __shared__ alignas(16) unsigned short K_lds[3*64*64];
  __shared__ alignas(16) unsigned short V_lds[3*64*64];
  __shared__ alignas(16) unsigned short P_lds[4*32*72];
  const int tid  = threadIdx.x;
  const int lane = tid & 63, wid = tid >> 6;
  const int l15  = lane & 15, lhi = lane >> 4;
  const int qt   = (int)gridDim.x - 1 - (int)blockIdx.x;  // longest first (LPT)
  const int bh   = blockIdx.y;
  const size_t base = (size_t)bh * 2048 * 64;
  const int q0w  = qt*128 + wid*32;
  const int qmaxw = q0w + 31;

  // staging: thread -> rows sr, sr+32; source chunk pre-swizzled so that
  // LDS slot (row, cs) holds global chunk cs ^ (row&7)
  const int sr  = tid >> 3;
  const int sck = (tid & 7) ^ (sr & 7);
  const unsigned short* kg0 = kbuf + base + (size_t)(sr     )*64 + sck*8;
  const unsigned short* kg1 = kbuf + base + (size_t)(sr + 32)*64 + sck*8;
  const unsigned short* vg0 = vT   + base + (size_t)(sr     )*2048 + sck*8;
  const unsigned short* vg1 = vT   + base + (size_t)(sr + 32)*2048 + sck*8;

#define A_STAGE(t, b) do {                                   \
    const int _kb = (t)*64;                                  \
    unsigned short* _kd = K_lds + (b)*4096;                  \
    unsigned short* _vd = V_lds + (b)*4096;                  \
    gload16(kg0 + (size_t)_kb*64, _kd + tid*8);              \
    gload16(kg1 + (size_t)_kb*64, _kd + 2048 + tid*8);       \
    gload16(vg0 + _kb,            _vd + tid*8);              \
    gload16(vg1 + _kb,            _vd + 2048 + tid*8);       \
  } while(0)

  // Q fragments: 2 column groups x 2 k-chunks
  short8 qf[2][2];
  #pragma unroll
  for (int g = 0; g < 2; ++g)
    #pragma unroll
    for (int i = 0; i < 2; ++i)
      qf[g][i] = *(const short8*)(qb + base + (size_t)(q0w + g*16 + l15)*64 + i*32 + lhi*8);

  float m_run[2] = {-1e30f, -1e30f};
  float l_run[2] = {0.f, 0.f};
  f32x4 o_acc[2][4] = {};
  unsigned short* Pw = P_lds + wid*32*72;

  const int nkt = 2*qt + 2;   // always >= 2

  // prologue: 2-deep prefetch
  A_STAGE(0, 0);
  A_STAGE(1, 1);

  int cb = 0, sb = 2;
  for (int kt = 0; kt < nkt; ++kt){
    asm volatile("s_waitcnt vmcnt(4)" ::: "memory");   // tile kt's loads done (own wave)
    __builtin_amdgcn_s_barrier();                      // ... and across all waves
    if (kt + 2 < nkt) A_STAGE(kt + 2, sb);
    if (kt*64 <= qmaxw){   // wave-uniform skip of fully-masked diagonal tiles
      const unsigned short* Kc = K_lds + cb*4096;
      const unsigned short* Vc = V_lds + cb*4096;
      // ---- S^T = K Q^T per group: row=k(lhi*4+j within fn*16), col=q(l15) ----
      short8 kf[4][2];
      #pragma unroll
      for (int fn = 0; fn < 4; ++fn)
        #pragma unroll
        for (int i = 0; i < 2; ++i)
          kf[fn][i] = *(const short8*)(Kc + (fn*16 + l15)*64 + (((i*4 + lhi) ^ (l15 & 7)) << 3));
      f32x4 s[2][4] = {};
      __builtin_amdgcn_s_setprio(1);
      #pragma unroll
      for (int g = 0; g < 2; ++g)
        #pragma unroll
        for (int fn = 0; fn < 4; ++fn)
          #pragma unroll
          for (int i = 0; i < 2; ++i)
            s[g][fn] = __builtin_amdgcn_mfma_f32_16x16x32_bf16(kf[fn][i], qf[g][i], s[g][fn], 0, 0, 0);
      __builtin_amdgcn_s_setprio(0);
      // ---- causal mask (diagonal region only) ----
      if (kt >= 2*qt){
        #pragma unroll
        for (int g = 0; g < 2; ++g){
          const int qi = q0w + g*16 + l15;
          #pragma unroll
          for (int fn = 0; fn < 4; ++fn)
            #pragma unroll
            for (int j = 0; j < 4; ++j){
              int ki = kt*64 + fn*16 + lhi*4 + j;
              if (ki > qi) s[g][fn][j] = -1e30f;
            }
        }
      }
      // ---- per-group row max (in-lane 16 + 2 shfl) ----
      float rmax[2];
      #pragma unroll
      for (int g = 0; g < 2; ++g){
        float t0 = fmaxf(fmaxf(s[g][0][0], s[g][0][1]), fmaxf(s[g][0][2], s[g][0][3]));
        float t1 = fmaxf(fmaxf(s[g][1][0], s[g][1][1]), fmaxf(s[g][1][2], s[g][1][3]));
        float t2 = fmaxf(fmaxf(s[g][2][0], s[g][2][1]), fmaxf(s[g][2][2], s[g][2][3]));
        float t3 = fmaxf(fmaxf(s[g][3][0], s[g][3][1]), fmaxf(s[g][3][2], s[g][3][3]));
        float v = fmaxf(fmaxf(t0, t1), fmaxf(t2, t3));
        v = fmaxf(v, __shfl_xor(v, 16));
        v = fmaxf(v, __shfl_xor(v, 32));
        rmax[g] = v;
      }
      // ---- defer-max: rescale only when max grows past THR=8 (log2 units) ----
      bool need = (rmax[0] > m_run[0] + 8.f) || (rmax[1] > m_run[1] + 8.f);
      if (__any(need)){
        #pragma unroll
        for (int g = 0; g < 2; ++g){
          float mn   = fmaxf(m_run[g], rmax[g]);
          float corr = exp2f(m_run[g] - mn);
          m_run[g] = mn;
          l_run[g] *= corr;
          #pragma unroll
          for (int j = 0; j < 4; ++j){
            float cj = __shfl(corr, (lane & 48) | (lhi*4 + j));
            #pragma unroll
            for (int df = 0; df < 4; ++df) o_acc[g][df][j] *= cj;
          }
        }
      }
      // ---- P = exp2(S - m), pack bf16, accumulate row sums ----
      #pragma unroll
      for (int g = 0; g < 2; ++g){
        const float mr = m_run[g];
        float rsum = 0.f;
        unsigned long long pwq[4];
        #pragma unroll
        for (int fn = 0; fn < 4; ++fn){
          float e0 = exp2f(s[g][fn][0] - mr);
          float e1 = exp2f(s[g][fn][1] - mr);
          float e2 = exp2f(s[g][fn][2] - mr);
          float e3 = exp2f(s[g][fn][3] - mr);
          rsum += (e0 + e1) + (e2 + e3);
          unsigned int w0 = (unsigned int)f2brn(e0) | ((unsigned int)f2brn(e1) << 16);
          unsigned int w1 = (unsigned int)f2brn(e2) | ((unsigned int)f2brn(e3) << 16);
          pwq[fn] = (unsigned long long)w0 | ((unsigned long long)w1 << 32);
        }
        rsum += __shfl_xor(rsum, 16);
        rsum += __shfl_xor(rsum, 32);
        l_run[g] += rsum;
        #pragma unroll
        for (int fn = 0; fn < 4; ++fn)
          *(unsigned long long*)(Pw + (g*16 + l15)*72 + fn*16 + lhi*4) = pwq[fn];
      }
      // ---- O += P V ----
      short8 pa[2][2];
      #pragma unroll
      for (int g = 0; g < 2; ++g)
        #pragma unroll
        for (int i = 0; i < 2; ++i)
          pa[g][i] = *(const short8*)(Pw + (g*16 + l15)*72 + i*32 + lhi*8);
      __builtin_amdgcn_s_setprio(1);
      #pragma unroll
      for (int df = 0; df < 4; ++df){
        #pragma unroll
        for (int i = 0; i < 2; ++i){
          short8 vf = *(const short8*)(Vc + (df*16 + l15)*64 + (((i*4 + lhi) ^ (l15 & 7)) << 3));
          #pragma unroll
          for (int g = 0; g < 2; ++g)
            o_acc[g][df] = __builtin_amdgcn_mfma_f32_16x16x32_bf16(pa[g][i], vf, o_acc[g][df], 0, 0, 0);
        }
      }
      __builtin_amdgcn_s_setprio(0);
    }
    cb = (cb == 2) ? 0 : cb + 1;
    sb = (sb == 2) ? 0 : sb + 1;
  }
#undef A_STAGE
  // ---- normalize + write [B,T,H*hd] bf16 ----
  const int b = bh >> 4, h = bh & 15;
  #pragma unroll
  for (int g = 0; g < 2; ++g){
    float rln = 1.0f / l_run[g];
    #pragma unroll
    for (int j = 0; j < 4; ++j){
      float rl = __shfl(rln, (lane & 48) | (lhi*4 + j));
      int qrow = q0w + g*16 + lhi*4 + j;
      #pragma unroll
      for (int df = 0; df < 4; ++df){
        float v = o_acc[g][df][j] * rl;
        ao[(size_t)(b*2048 + qrow)*1024 + h*64 + df*16 + l15] = f2brn(v);
      }
    }
  }
}

extern "C" void kernel_launch(void* const* d_in, const int* in_sizes, int n_in,
                              void* d_out, int out_size, void* d_ws, size_t ws_size,
                              hipStream_t stream){
  const float* x     = (const float*)d_in[0];
  const float* Wqkv  = (const float*)d_in[1];
  const float* bqkv  = (const float*)d_in[2];
  const float* Wproj = (const float*)d_in[3];
  const float* bproj = (const float*)d_in[4];
  float* out = (float*)d_out;

  unsigned short* ws     = (unsigned short*)d_ws;
  unsigned short* xb     = ws;                       // 8192*1024
  unsigned short* wqkvT  = xb + 8388608;             // 3072*1024
  unsigned short* wprojT = wqkvT + 3145728;          // 1024*1024
  unsigned short* qbuf   = wprojT + 1048576;         // [B,H,T,64]
  unsigned short* kbuf   = qbuf + 8388608;
  unsigned short* vbuf   = kbuf + 8388608;           // [B,H,64,T] (transposed)
  unsigned short* ao     = vbuf + 8388608;           // [B,T,1024]

  k_cast_x<<<8192, 256, 0, stream>>>(x, xb, 2097152);
  k_transpose_cast<<<dim3(96, 32), dim3(32, 8), 0, stream>>>(Wqkv, wqkvT, 1024, 3072);
  k_transpose_cast<<<dim3(32, 32), dim3(32, 8), 0, stream>>>(Wproj, wprojT, 1024, 1024);
  k_gemm_bt<0><<<dim3(24, 64), 256, 0, stream>>>(xb, wqkvT, bqkv, nullptr,
                                                 qbuf, kbuf, vbuf, 8192, 3072, 1024);
  k_attn<<<dim3(16, 64), 256, 0, stream>>>(qbuf, kbuf, vbuf, ao);
  k_gemm_bt<1><<<dim3(8, 64), 256, 0, stream>>>(ao, wprojT, bproj, out,
                                                nullptr, nullptr, nullptr, 8192, 1024, 1024);
}

// Round 6
// 368.521 us; speedup vs baseline: 1.8204x; 1.0456x over previous
//
#include <hip/hip_runtime.h>
#include <hip/hip_bf16.h>

typedef __attribute__((ext_vector_type(8))) short short8;
typedef __attribute__((ext_vector_type(4))) float f32x4;

// 1/sqrt(64) * log2(e): fold softmax base-2 conversion into Q scale
#define QSCALE 0.1803368801111204f

__device__ inline unsigned short f2b(float f){
  union { float f; unsigned int u; } a; a.f = f;
  unsigned int u = a.u;
  unsigned int r = (u + 0x7fff + ((u >> 16) & 1)) >> 16;
  return (unsigned short)r;
}

// RNE float->bf16 via HIP intrinsic: compiler can fuse pairs into v_cvt_pk_bf16_f32
__device__ inline unsigned short f2brn(float f){
  __hip_bfloat16 h = __float2bfloat16(f);
  union { __hip_bfloat16 h; unsigned short u; } c; c.h = h;
  return c.u;
}

// async global->LDS, 16B per lane (wave-uniform LDS base + lane*16)
__device__ inline void gload16(const unsigned short* g, unsigned short* l){
  __builtin_amdgcn_global_load_lds((const __attribute__((address_space(1))) void*)g,
                                   (__attribute__((address_space(3))) void*)l, 16, 0, 0);
}

__device__ inline unsigned long long shfl64(unsigned long long v, int src){
  int lo = __shfl((int)(unsigned)(v & 0xffffffffull), src);
  int hi = __shfl((int)(unsigned)(v >> 32), src);
  return ((unsigned long long)(unsigned)hi << 32) | (unsigned)(unsigned int)lo;
}

// ---------------- cast x -> bf16 ----------------
__global__ void k_cast_x(const float* __restrict__ x, unsigned short* __restrict__ xb, int n4){
  int i = blockIdx.x * blockDim.x + threadIdx.x;
  if (i < n4){
    float4 v = ((const float4*)x)[i];
    ushort4 o;
    o.x = f2b(v.x); o.y = f2b(v.y); o.z = f2b(v.z); o.w = f2b(v.w);
    ((ushort4*)xb)[i] = o;
  }
}

// ---------------- transpose + cast: in[R][Cc] f32 -> out[Cc][R] bf16 ----------------
__global__ void k_transpose_cast(const float* __restrict__ in, unsigned short* __restrict__ out,
                                 int R, int Cc){
  __shared__ float tile[32][33];
  int bx = blockIdx.x, by = blockIdx.y;
  int tx = threadIdx.x, ty = threadIdx.y;
  int col = bx*32 + tx;
  #pragma unroll
  for (int jj = 0; jj < 4; ++jj){
    int row = by*32 + ty + jj*8;
    tile[ty + jj*8][tx] = in[(size_t)row*Cc + col];
  }
  __syncthreads();
  int r = by*32 + tx;
  #pragma unroll
  for (int jj = 0; jj < 4; ++jj){
    int c = bx*32 + ty + jj*8;
    out[(size_t)c*R + r] = f2b(tile[tx][ty + jj*8]);
  }
}

// ---------------- GEMM: C = A[M][K] * Bt[N][K]^T + bias ----------------
// T3/T4 pipeline: 3 LDS buffers, global_load_lds width-16, counted vmcnt(4)
// (vmcnt(0) tail on the last step), ONE raw s_barrier per K-step.
// MODE 0: scatter q/k [B,H,T,hd] (Q scaled) + V^T [B,H,hd,T]. MODE 1: f32 [M][N].
template<int MODE>
__global__ __launch_bounds__(256) void k_gemm_bt(
    const unsigned short* __restrict__ A,
    const unsigned short* __restrict__ Bt,
    const float* __restrict__ bias,
    float* __restrict__ Cout,
    unsigned short* __restrict__ qb,
    unsigned short* __restrict__ kbf,
    unsigned short* __restrict__ vbf,
    int Mdim, int Ndim, int Kdim)
{
  __shared__ alignas(16) unsigned short As[3*128*32];
  __shared__ alignas(16) unsigned short Bs[3*128*32];
  const int tid  = threadIdx.x;
  const int lane = tid & 63;
  const int wid  = tid >> 6;
  const int wm   = wid >> 1, wn = wid & 1;
  const int bn   = blockIdx.x, bm = blockIdx.y;
  const int l15  = lane & 15, lhi = lane >> 4;

  f32x4 acc[4][4] = {};

  const int rowA0 = bm * 128, rowB0 = bn * 128;
  const unsigned short* Ag = A  + (size_t)(rowA0 + (tid>>2)) * Kdim + (tid&3)*8;
  const unsigned short* Bg = Bt + (size_t)(rowB0 + (tid>>2)) * Kdim + (tid&3)*8;
  const size_t row64 = (size_t)64 * Kdim;

  const int nK = Kdim >> 5;

#define G_STAGE(t, b) do {                                   \
    const int _ko = (t)*32;                                  \
    unsigned short* _as = As + (b)*4096;                     \
    unsigned short* _bs = Bs + (b)*4096;                     \
    gload16(Ag + _ko,         _as + tid*8);                  \
    gload16(Ag + row64 + _ko, _as + 2048 + tid*8);           \
    gload16(Bg + _ko,         _bs + tid*8);                  \
    gload16(Bg + row64 + _ko, _bs + 2048 + tid*8);           \
  } while(0)

  // prologue: 2-deep prefetch
  G_STAGE(0, 0);
  G_STAGE(1, 1);

  int cb = 0, sb = 2;
  for (int kt = 0; kt < nK; ++kt){
    if (kt + 1 < nK) { asm volatile("s_waitcnt vmcnt(4)" ::: "memory"); }
    else             { asm volatile("s_waitcnt vmcnt(0)" ::: "memory"); }
    __builtin_amdgcn_s_barrier();                      // all waves' tile-kt loads done
    if (kt + 2 < nK) G_STAGE(kt + 2, sb);
    const unsigned short* Ac = As + cb*4096;
    const unsigned short* Bc = Bs + cb*4096;
    short8 af[4], bfr[4];
    #pragma unroll
    for (int f = 0; f < 4; ++f){
      af[f]  = *(const short8*)(Ac + (wm*64 + f*16 + l15)*32 + lhi*8);
      bfr[f] = *(const short8*)(Bc + (wn*64 + f*16 + l15)*32 + lhi*8);
    }
    __builtin_amdgcn_s_setprio(1);
    #pragma unroll
    for (int fm = 0; fm < 4; ++fm)
      #pragma unroll
      for (int fn = 0; fn < 4; ++fn)
        acc[fm][fn] = __builtin_amdgcn_mfma_f32_16x16x32_bf16(af[fm], bfr[fn], acc[fm][fn], 0, 0, 0);
    __builtin_amdgcn_s_setprio(0);
    cb = (cb == 2) ? 0 : cb + 1;
    sb = (sb == 2) ? 0 : sb + 1;
  }
#undef G_STAGE

  #pragma unroll
  for (int fm = 0; fm < 4; ++fm){
    #pragma unroll
    for (int fn = 0; fn < 4; ++fn){
      int n  = bn*128 + wn*64 + fn*16 + l15;
      int m0 = bm*128 + wm*64 + fm*16 + lhi*4;
      if (MODE == 0){
        int which = n >> 10; int cc2 = n & 1023; int h = cc2 >> 6; int d = cc2 & 63;
        int bb = m0 >> 11;   int t0 = m0 & 2047;
        if (which == 2){
          // V transposed [B*H][64][2048]; j -> t contiguous: pack u64 store
          float bv = bias[n];
          unsigned long long pk = 0;
          #pragma unroll
          for (int j = 0; j < 4; ++j)
            pk |= (unsigned long long)f2b(acc[fm][fn][j] + bv) << (16*j);
          *(unsigned long long*)(vbf + ((size_t)(bb*16 + h)*64 + d)*2048 + t0) = pk;
        } else {
          unsigned short* dst = (which == 0) ? qb : kbf;
          float bv = bias[n];
          #pragma unroll
          for (int j = 0; j < 4; ++j){
            float v = acc[fm][fn][j] + bv;
            if (which == 0) v *= QSCALE;
            dst[(size_t)((bb*16 + h)*2048 + t0 + j)*64 + d] = f2b(v);
          }
        }
      } else {
        float bv = bias[n];
        #pragma unroll
        for (int j = 0; j < 4; ++j)
          Cout[(size_t)(m0 + j) * Ndim + n] = acc[fm][fn][j] + bv;
      }
    }
  }
}

// ---------------- causal flash attention ----------------
// grid (T/128, B*H), block 256 = 4 waves x 32 q-rows (2 column groups of 16).
// 2-buffer K/V (32KB LDS total, no P_lds -> 4 blocks/CU), counted vmcnt(4)
// with vmcnt(0) tail, 2 raw barriers/tile. P redistribution fully in-register
// via fixed-permutation shfl64 (ds_bpermute) -- no LDS round trip.
// Swapped QK^T -> in-lane softmax; defer-max THR=8 (log2 units).
__global__ __launch_bounds__(256) void k_attn(
    const unsigned short* __restrict__ qb,
    const unsigned short* __restrict__ kbuf,
    const unsigned short* __restrict__ vT,
    unsigned short* __restrict__ ao)
{
  __shared__ alignas(16) unsigned short K_lds[2*64*64];
  __shared__ alignas(16) unsigned short V_lds[2*64*64];
  const int tid  = threadIdx.x;
  const int lane = tid & 63, wid = tid >> 6;
  const int l15  = lane & 15, lhi = lane >> 4;
  const int qt   = (int)gridDim.x - 1 - (int)blockIdx.x;  // longest first (LPT)
  const int bh   = blockIdx.y;
  const size_t base = (size_t)bh * 2048 * 64;
  const int q0w  = qt*128 + wid*32;
  const int qmaxw = q0w + 31;

  // staging: thread -> rows sr, sr+32; source chunk pre-swizzled so that
  // LDS slot (row, cs) holds global chunk cs ^ (row&7)
  const int sr  = tid >> 3;
  const int sck = (tid & 7) ^ (sr & 7);
  const unsigned short* kg0 = kbuf + base + (size_t)(sr     )*64 + sck*8;
  const unsigned short* kg1 = kbuf + base + (size_t)(sr + 32)*64 + sck*8;
  const unsigned short* vg0 = vT   + base + (size_t)(sr     )*2048 + sck*8;
  const unsigned short* vg1 = vT   + base + (size_t)(sr + 32)*2048 + sck*8;

#define A_STAGE(t, b) do {                                   \
    const int _kb = (t)*64;                                  \
    unsigned short* _kd = K_lds + (b)*4096;                  \
    unsigned short* _vd = V_lds + (b)*4096;                  \
    gload16(kg0 + (size_t)_kb*64, _kd + tid*8);              \
    gload16(kg1 + (size_t)_kb*64, _kd + 2048 + tid*8);       \
    gload16(vg0 + _kb,            _vd + tid*8);              \
    gload16(vg1 + _kb,            _vd + 2048 + tid*8);       \
  } while(0)

  // Q fragments: 2 column groups x 2 k-chunks
  short8 qf[2][2];
  #pragma unroll
  for (int g = 0; g < 2; ++g)
    #pragma unroll
    for (int i = 0; i < 2; ++i)
      qf[g][i] = *(const short8*)(qb + base + (size_t)(q0w + g*16 + l15)*64 + i*32 + lhi*8);

  float m_run[2] = {-1e30f, -1e30f};
  float l_run[2] = {0.f, 0.f};
  f32x4 o_acc[2][4] = {};

  const int nkt = 2*qt + 2;   // always >= 2

  // fixed shuffle-permutation constants (bit-swap of lhi)
  const int bs = ((lhi & 1) << 1) | (lhi >> 1);
  const int sA = l15 + (bs << 4);
  const int sB = l15 + ((bs ^ 1) << 4);
  const bool selodd = (lhi & 1);
  const bool lowh   = (lhi < 2);

  // prologue: stage tile 0 into buffer 0
  A_STAGE(0, 0);

  for (int kt = 0; kt < nkt; ++kt){
    if (kt + 1 < nkt){
      A_STAGE(kt + 1, (kt + 1) & 1);
      asm volatile("s_waitcnt vmcnt(4)" ::: "memory");   // tile kt's loads done
    } else {
      asm volatile("s_waitcnt vmcnt(0)" ::: "memory");
    }
    __builtin_amdgcn_s_barrier();                        // ... across all waves
    if (kt*64 <= qmaxw){   // skip fully-masked diagonal tiles (per-wave uniform)
      const unsigned short* Kc = K_lds + (kt & 1)*4096;
      const unsigned short* Vc = V_lds + (kt & 1)*4096;
      // ---- S^T = K Q^T per group: row=k(fn*16+lhi*4+j), col=q(l15) ----
      short8 kf[4][2];
      #pragma unroll
      for (int fn = 0; fn < 4; ++fn)
        #pragma unroll
        for (int i = 0; i < 2; ++i)
          kf[fn][i] = *(const short8*)(Kc + (fn*16 + l15)*64 + (((i*4 + lhi) ^ (l15 & 7)) << 3));
      f32x4 s[2][4] = {};
      __builtin_amdgcn_s_setprio(1);
      #pragma unroll
      for (int g = 0; g < 2; ++g)
        #pragma unroll
        for (int fn = 0; fn < 4; ++fn)
          #pragma unroll
          for (int i = 0; i < 2; ++i)
            s[g][fn] = __builtin_amdgcn_mfma_f32_16x16x32_bf16(kf[fn][i], qf[g][i], s[g][fn], 0, 0, 0);
      __builtin_amdgcn_s_setprio(0);
      // ---- causal mask (diagonal region only) ----
      if (kt >= 2*qt){
        #pragma unroll
        for (int g = 0; g < 2; ++g){
          const int qi = q0w + g*16 + l15;
          #pragma unroll
          for (int fn = 0; fn < 4; ++fn)
            #pragma unroll
            for (int j = 0; j < 4; ++j){
              int ki = kt*64 + fn*16 + lhi*4 + j;
              if (ki > qi) s[g][fn][j] = -1e30f;
            }
        }
      }
      // ---- per-group row max (in-lane 16 + 2 shfl) ----
      float rmax[2];
      #pragma unroll
      for (int g = 0; g < 2; ++g){
        float t0 = fmaxf(fmaxf(s[g][0][0], s[g][0][1]), fmaxf(s[g][0][2], s[g][0][3]));
        float t1 = fmaxf(fmaxf(s[g][1][0], s[g][1][1]), fmaxf(s[g][1][2], s[g][1][3]));
        float t2 = fmaxf(fmaxf(s[g][2][0], s[g][2][1]), fmaxf(s[g][2][2], s[g][2][3]));
        float t3 = fmaxf(fmaxf(s[g][3][0], s[g][3][1]), fmaxf(s[g][3][2], s[g][3][3]));
        float v = fmaxf(fmaxf(t0, t1), fmaxf(t2, t3));
        v = fmaxf(v, __shfl_xor(v, 16));
        v = fmaxf(v, __shfl_xor(v, 32));
        rmax[g] = v;
      }
      // ---- defer-max: rescale only when max grows past THR=8 (log2 units) ----
      bool need = (rmax[0] > m_run[0] + 8.f) || (rmax[1] > m_run[1] + 8.f);
      if (__any(need)){
        #pragma unroll
        for (int g = 0; g < 2; ++g){
          float mn   = fmaxf(m_run[g], rmax[g]);
          float corr = exp2f(m_run[g] - mn);
          m_run[g] = mn;
          l_run[g] *= corr;
          #pragma unroll
          for (int j = 0; j < 4; ++j){
            float cj = __shfl(corr, (lane & 48) | (lhi*4 + j));
            #pragma unroll
            for (int df = 0; df < 4; ++df) o_acc[g][df][j] *= cj;
          }
        }
      }
      // ---- P = exp2(S - m), pack bf16 b64 per fn, accumulate row sums ----
      unsigned long long pwq[2][4];
      #pragma unroll
      for (int g = 0; g < 2; ++g){
        const float mr = m_run[g];
        float rsum = 0.f;
        #pragma unroll
        for (int fn = 0; fn < 4; ++fn){
          float e0 = exp2f(s[g][fn][0] - mr);
          float e1 = exp2f(s[g][fn][1] - mr);
          float e2 = exp2f(s[g][fn][2] - mr);
          float e3 = exp2f(s[g][fn][3] - mr);
          rsum += (e0 + e1) + (e2 + e3);
          unsigned int w0 = (unsigned int)f2brn(e0) | ((unsigned int)f2brn(e1) << 16);
          unsigned int w1 = (unsigned int)f2brn(e2) | ((unsigned int)f2brn(e3) << 16);
          pwq[g][fn] = (unsigned long long)w0 | ((unsigned long long)w1 << 32);
        }
        rsum += __shfl_xor(rsum, 16);
        rsum += __shfl_xor(rsum, 32);
        l_run[g] += rsum;
      }
      // ---- in-register P^T -> A-frag redistribution (fixed permutation) ----
      // target lane (q=l15, lhi), chunk i: lo64 = pwq[2i+(lhi>>1)] @ lane l15+16*((2lhi)&3)
      //                                    hi64 = pwq[2i+(lhi>>1)] @ lane l15+16*((2lhi+1)&3)
      // round A: src publishes pwq[2i + (src_lhi&1)], read from sA (bit-swapped lhi)
      // round B: src publishes pwq[2i + !(src_lhi&1)], read from sB (= sA^16... bs^1)
      short8 pa[2][2];
      #pragma unroll
      for (int g = 0; g < 2; ++g){
        unsigned long long pubA0 = selodd ? pwq[g][1] : pwq[g][0];
        unsigned long long pubB0 = selodd ? pwq[g][0] : pwq[g][1];
        unsigned long long pubA1 = selodd ? pwq[g][3] : pwq[g][2];
        unsigned long long pubB1 = selodd ? pwq[g][2] : pwq[g][3];
        unsigned long long rA0 = shfl64(pubA0, sA);
        unsigned long long rB0 = shfl64(pubB0, sB);
        unsigned long long rA1 = shfl64(pubA1, sA);
        unsigned long long rB1 = shfl64(pubB1, sB);
        union { unsigned long long q[2]; short8 v; } u0, u1;
        u0.q[0] = lowh ? rA0 : rB0;  u0.q[1] = lowh ? rB0 : rA0;
        u1.q[0] = lowh ? rA1 : rB1;  u1.q[1] = lowh ? rB1 : rA1;
        pa[g][0] = u0.v;  pa[g][1] = u1.v;
      }
      // ---- O += P V ----
      __builtin_amdgcn_s_setprio(1);
      #pragma unroll
      for (int df = 0; df < 4; ++df){
        #pragma unroll
        for (int i = 0; i < 2; ++i){
          short8 vf = *(const short8*)(Vc + (df*16 + l15)*64 + (((i*4 + lhi) ^ (l15 & 7)) << 3));
          #pragma unroll
          for (int g = 0; g < 2; ++g)
            o_acc[g][df] = __builtin_amdgcn_mfma_f32_16x16x32_bf16(pa[g][i], vf, o_acc[g][df], 0, 0, 0);
        }
      }
      __builtin_amdgcn_s_setprio(0);
    }
    __builtin_amdgcn_s_barrier();   // all waves done reading buf before re-stage
  }
#undef A_STAGE
  // ---- normalize + write [B,T,H*hd] bf16 ----
  const int b = bh >> 4, h = bh & 15;
  #pragma unroll
  for (int g = 0; g < 2; ++g){
    float rln = 1.0f / l_run[g];
    #pragma unroll
    for (int j = 0; j < 4; ++j){
      float rl = __shfl(rln, (lane & 48) | (lhi*4 + j));
      int qrow = q0w + g*16 + lhi*4 + j;
      #pragma unroll
      for (int df = 0; df < 4; ++df){
        float v = o_acc[g][df][j] * rl;
        ao[(size_t)(b*2048 + qrow)*1024 + h*64 + df*16 + l15] = f2brn(v);
      }
    }
  }
}

extern "C" void kernel_launch(void* const* d_in, const int* in_sizes, int n_in,
                              void* d_out, int out_size, void* d_ws, size_t ws_size,
                              hipStream_t stream){
  const float* x     = (const float*)d_in[0];
  const float* Wqkv  = (const float*)d_in[1];
  const float* bqkv  = (const float*)d_in[2];
  const float* Wproj = (const float*)d_in[3];
  const float* bproj = (const float*)d_in[4];
  float* out = (float*)d_out;

  unsigned short* ws     = (unsigned short*)d_ws;
  unsigned short* xb     = ws;                       // 8192*1024
  unsigned short* wqkvT  = xb + 8388608;             // 3072*1024
  unsigned short* wprojT = wqkvT + 3145728;          // 1024*1024
  unsigned short* qbuf   = wprojT + 1048576;         // [B,H,T,64]
  unsigned short* kbuf   = qbuf + 8388608;
  unsigned short* vbuf   = kbuf + 8388608;           // [B,H,64,T] (transposed)
  unsigned short* ao     = vbuf + 8388608;           // [B,T,1024]

  k_cast_x<<<8192, 256, 0, stream>>>(x, xb, 2097152);
  k_transpose_cast<<<dim3(96, 32), dim3(32, 8), 0, stream>>>(Wqkv, wqkvT, 1024, 3072);
  k_transpose_cast<<<dim3(32, 32), dim3(32, 8), 0, stream>>>(Wproj, wprojT, 1024, 1024);
  k_gemm_bt<0><<<dim3(24, 64), 256, 0, stream>>>(xb, wqkvT, bqkv, nullptr,
                                                 qbuf, kbuf, vbuf, 8192, 3072, 1024);
  k_attn<<<dim3(16, 64), 256, 0, stream>>>(qbuf, kbuf, vbuf, ao);
  k_gemm_bt<1><<<dim3(8, 64), 256, 0, stream>>>(ao, wprojT, bproj, out,
                                                nullptr, nullptr, nullptr, 8192, 1024, 1024);
}

// Round 7
// 353.383 us; speedup vs baseline: 1.8984x; 1.0428x over previous
//
#include <hip/hip_runtime.h>
#include <hip/hip_bf16.h>

typedef __attribute__((ext_vector_type(8))) short short8;
typedef __attribute__((ext_vector_type(4))) float f32x4;
typedef __attribute__((ext_vector_type(16))) float f32x16;

// 1/sqrt(64) * log2(e): fold softmax base-2 conversion into Q scale
#define QSCALE 0.1803368801111204f

__device__ inline unsigned short f2b(float f){
  union { float f; unsigned int u; } a; a.f = f;
  unsigned int u = a.u;
  unsigned int r = (u + 0x7fff + ((u >> 16) & 1)) >> 16;
  return (unsigned short)r;
}

// RNE float->bf16 via HIP intrinsic: compiler fuses pairs into v_cvt_pk_bf16_f32
__device__ inline unsigned short f2brn(float f){
  __hip_bfloat16 h = __float2bfloat16(f);
  union { __hip_bfloat16 h; unsigned short u; } c; c.h = h;
  return c.u;
}
__device__ inline unsigned pk2(float lo, float hi){
  return (unsigned)f2brn(lo) | ((unsigned)f2brn(hi) << 16);
}

// async global->LDS, 16B per lane (wave-uniform LDS base + lane*16)
__device__ inline void gload16(const unsigned short* g, unsigned short* l){
  __builtin_amdgcn_global_load_lds((const __attribute__((address_space(1))) void*)g,
                                   (__attribute__((address_space(3))) void*)l, 16, 0, 0);
}

// ---------------- cast x -> bf16 ----------------
__global__ void k_cast_x(const float* __restrict__ x, unsigned short* __restrict__ xb, int n4){
  int i = blockIdx.x * blockDim.x + threadIdx.x;
  if (i < n4){
    float4 v = ((const float4*)x)[i];
    ushort4 o;
    o.x = f2b(v.x); o.y = f2b(v.y); o.z = f2b(v.z); o.w = f2b(v.w);
    ((ushort4*)xb)[i] = o;
  }
}

// ---------------- transpose + cast: in[R][Cc] f32 -> out[Cc][R] bf16 ----------------
__global__ void k_transpose_cast(const float* __restrict__ in, unsigned short* __restrict__ out,
                                 int R, int Cc){
  __shared__ float tile[32][33];
  int bx = blockIdx.x, by = blockIdx.y;
  int tx = threadIdx.x, ty = threadIdx.y;
  int col = bx*32 + tx;
  #pragma unroll
  for (int jj = 0; jj < 4; ++jj){
    int row = by*32 + ty + jj*8;
    tile[ty + jj*8][tx] = in[(size_t)row*Cc + col];
  }
  __syncthreads();
  int r = by*32 + tx;
  #pragma unroll
  for (int jj = 0; jj < 4; ++jj){
    int c = bx*32 + ty + jj*8;
    out[(size_t)c*R + r] = f2b(tile[tx][ty + jj*8]);
  }
}

// ---------------- GEMM: C = A[M][K] * Bt[N][K]^T + bias ----------------
// T3/T4 pipeline: 3 LDS buffers, global_load_lds width-16, counted vmcnt(4)
// (vmcnt(0) tail on the last step), ONE raw s_barrier per K-step.
// MODE 0: scatter q/k [B,H,T,hd] (Q scaled) + V^T [B,H,hd,T]. MODE 1: f32 [M][N].
template<int MODE>
__global__ __launch_bounds__(256) void k_gemm_bt(
    const unsigned short* __restrict__ A,
    const unsigned short* __restrict__ Bt,
    const float* __restrict__ bias,
    float* __restrict__ Cout,
    unsigned short* __restrict__ qb,
    unsigned short* __restrict__ kbf,
    unsigned short* __restrict__ vbf,
    int Mdim, int Ndim, int Kdim)
{
  __shared__ alignas(16) unsigned short As[3*128*32];
  __shared__ alignas(16) unsigned short Bs[3*128*32];
  const int tid  = threadIdx.x;
  const int lane = tid & 63;
  const int wid  = tid >> 6;
  const int wm   = wid >> 1, wn = wid & 1;
  const int bn   = blockIdx.x, bm = blockIdx.y;
  const int l15  = lane & 15, lhi = lane >> 4;

  f32x4 acc[4][4] = {};

  const int rowA0 = bm * 128, rowB0 = bn * 128;
  const unsigned short* Ag = A  + (size_t)(rowA0 + (tid>>2)) * Kdim + (tid&3)*8;
  const unsigned short* Bg = Bt + (size_t)(rowB0 + (tid>>2)) * Kdim + (tid&3)*8;
  const size_t row64 = (size_t)64 * Kdim;

  const int nK = Kdim >> 5;

#define G_STAGE(t, b) do {                                   \
    const int _ko = (t)*32;                                  \
    unsigned short* _as = As + (b)*4096;                     \
    unsigned short* _bs = Bs + (b)*4096;                     \
    gload16(Ag + _ko,         _as + tid*8);                  \
    gload16(Ag + row64 + _ko, _as + 2048 + tid*8);           \
    gload16(Bg + _ko,         _bs + tid*8);                  \
    gload16(Bg + row64 + _ko, _bs + 2048 + tid*8);           \
  } while(0)

  // prologue: 2-deep prefetch
  G_STAGE(0, 0);
  G_STAGE(1, 1);

  int cb = 0, sb = 2;
  for (int kt = 0; kt < nK; ++kt){
    if (kt + 1 < nK) { asm volatile("s_waitcnt vmcnt(4)" ::: "memory"); }
    else             { asm volatile("s_waitcnt vmcnt(0)" ::: "memory"); }
    __builtin_amdgcn_s_barrier();                      // all waves' tile-kt loads done
    if (kt + 2 < nK) G_STAGE(kt + 2, sb);
    const unsigned short* Ac = As + cb*4096;
    const unsigned short* Bc = Bs + cb*4096;
    short8 af[4], bfr[4];
    #pragma unroll
    for (int f = 0; f < 4; ++f){
      af[f]  = *(const short8*)(Ac + (wm*64 + f*16 + l15)*32 + lhi*8);
      bfr[f] = *(const short8*)(Bc + (wn*64 + f*16 + l15)*32 + lhi*8);
    }
    __builtin_amdgcn_s_setprio(1);
    #pragma unroll
    for (int fm = 0; fm < 4; ++fm)
      #pragma unroll
      for (int fn = 0; fn < 4; ++fn)
        acc[fm][fn] = __builtin_amdgcn_mfma_f32_16x16x32_bf16(af[fm], bfr[fn], acc[fm][fn], 0, 0, 0);
    __builtin_amdgcn_s_setprio(0);
    cb = (cb == 2) ? 0 : cb + 1;
    sb = (sb == 2) ? 0 : sb + 1;
  }
#undef G_STAGE

  #pragma unroll
  for (int fm = 0; fm < 4; ++fm){
    #pragma unroll
    for (int fn = 0; fn < 4; ++fn){
      int n  = bn*128 + wn*64 + fn*16 + l15;
      int m0 = bm*128 + wm*64 + fm*16 + lhi*4;
      if (MODE == 0){
        int which = n >> 10; int cc2 = n & 1023; int h = cc2 >> 6; int d = cc2 & 63;
        int bb = m0 >> 11;   int t0 = m0 & 2047;
        if (which == 2){
          // V transposed [B*H][64][2048]; j -> t contiguous: pack u64 store
          float bv = bias[n];
          unsigned long long pk = 0;
          #pragma unroll
          for (int j = 0; j < 4; ++j)
            pk |= (unsigned long long)f2b(acc[fm][fn][j] + bv) << (16*j);
          *(unsigned long long*)(vbf + ((size_t)(bb*16 + h)*64 + d)*2048 + t0) = pk;
        } else {
          unsigned short* dst = (which == 0) ? qb : kbf;
          float bv = bias[n];
          #pragma unroll
          for (int j = 0; j < 4; ++j){
            float v = acc[fm][fn][j] + bv;
            if (which == 0) v *= QSCALE;
            dst[(size_t)((bb*16 + h)*2048 + t0 + j)*64 + d] = f2b(v);
          }
        }
      } else {
        float bv = bias[n];
        #pragma unroll
        for (int j = 0; j < 4; ++j)
          Cout[(size_t)(m0 + j) * Ndim + n] = acc[fm][fn][j] + bv;
      }
    }
  }
}

// ---------------- causal flash attention (32x32 MFMA, lane-local softmax) ----------------
// grid (T/128, B*H), block 256 = 4 waves x 32 q-rows. LPT (qt descending).
// S^T = mfma_32x32x16(K,Q): each lane owns ONE q-row's 32 k-values -> softmax
// reductions are in-lane + one shfl_xor(32); rescale/normalize are pure in-lane.
// P^T -> PV B-frag via 16 cvt_pk + 8 v_permlane32_swap (lane&31-preserving).
// K/V double-buffered via global_load_lds, pre-swizzled source chunks,
// counted vmcnt(4) with vmcnt(0) tail, 2 raw barriers/tile.
__global__ __launch_bounds__(256) void k_attn(
    const unsigned short* __restrict__ qb,
    const unsigned short* __restrict__ kbuf,
    const unsigned short* __restrict__ vT,
    unsigned short* __restrict__ ao)
{
  __shared__ alignas(16) unsigned short K_lds[2*64*64];
  __shared__ alignas(16) unsigned short V_lds[2*64*64];
  const int tid  = threadIdx.x;
  const int lane = tid & 63, wid = tid >> 6;
  const int l31  = lane & 31, h = lane >> 5;
  const int qt   = (int)gridDim.x - 1 - (int)blockIdx.x;  // longest first (LPT)
  const int bh   = blockIdx.y;
  const size_t base = (size_t)bh * 2048 * 64;
  const int q0w  = qt*128 + wid*32;
  const int qmaxw = q0w + 31;
  const int myq  = q0w + l31;

  // staging: thread -> rows sr, sr+32; source chunk pre-swizzled so that
  // LDS slot (row, cs) holds global chunk cs ^ (row&7)
  const int sr  = tid >> 3;
  const int sck = (tid & 7) ^ (sr & 7);
  const unsigned short* kg0 = kbuf + base + (size_t)(sr     )*64 + sck*8;
  const unsigned short* kg1 = kbuf + base + (size_t)(sr + 32)*64 + sck*8;
  const unsigned short* vg0 = vT   + base + (size_t)(sr     )*2048 + sck*8;
  const unsigned short* vg1 = vT   + base + (size_t)(sr + 32)*2048 + sck*8;

#define A_STAGE(t, b) do {                                   \
    const int _kb = (t)*64;                                  \
    unsigned short* _kd = K_lds + (b)*4096;                  \
    unsigned short* _vd = V_lds + (b)*4096;                  \
    gload16(kg0 + (size_t)_kb*64, _kd + tid*8);              \
    gload16(kg1 + (size_t)_kb*64, _kd + 2048 + tid*8);       \
    gload16(vg0 + _kb,            _vd + tid*8);              \
    gload16(vg1 + _kb,            _vd + 2048 + tid*8);       \
  } while(0)

  // Q B-frags: chunk c covers head-dim k = c*16 + h*8 + e
  short8 qf[4];
  #pragma unroll
  for (int c = 0; c < 4; ++c)
    qf[c] = *(const short8*)(qb + base + (size_t)myq*64 + c*16 + h*8);

  float m_run = -1e30f, l_run = 0.f;
  f32x16 oa0 = {}, oa1 = {};   // O^T accumulators: d-blocks 0..31, 32..63

  const int nkt = 2*qt + 2;   // always >= 2
  const int swr = (l31 & 7);  // swizzle key for fragment rows (row&7; +32 preserves)

  // prologue: stage tile 0 into buffer 0
  A_STAGE(0, 0);

  for (int kt = 0; kt < nkt; ++kt){
    if (kt + 1 < nkt){
      A_STAGE(kt + 1, (kt + 1) & 1);
      asm volatile("s_waitcnt vmcnt(4)" ::: "memory");   // tile kt's loads done
    } else {
      asm volatile("s_waitcnt vmcnt(0)" ::: "memory");
    }
    __builtin_amdgcn_s_barrier();                        // ... across all waves
    if (kt*64 <= qmaxw){   // skip fully-masked diagonal tiles (wave-uniform)
      const unsigned short* Kc = K_lds + (kt & 1)*4096;
      const unsigned short* Vc = V_lds + (kt & 1)*4096;
      // ---- K A-frags: k-rows l31 (blk0) and 32+l31 (blk1), d-chunk (2c+h)^swz ----
      short8 kf0[4], kf1[4];
      #pragma unroll
      for (int c = 0; c < 4; ++c){
        const int ch = ((2*c + h) ^ swr) << 3;
        kf0[c] = *(const short8*)(Kc + (l31     )*64 + ch);
        kf1[c] = *(const short8*)(Kc + (l31 + 32)*64 + ch);
      }
      // ---- S^T = K Q^T: col=q=l31 (all regs same q!), row=k=(r&3)+8(r>>2)+4h ----
      f32x16 s0 = {}, s1 = {};
      __builtin_amdgcn_s_setprio(1);
      #pragma unroll
      for (int c = 0; c < 4; ++c)
        s0 = __builtin_amdgcn_mfma_f32_32x32x16_bf16(kf0[c], qf[c], s0, 0, 0, 0);
      #pragma unroll
      for (int c = 0; c < 4; ++c)
        s1 = __builtin_amdgcn_mfma_f32_32x32x16_bf16(kf1[c], qf[c], s1, 0, 0, 0);
      __builtin_amdgcn_s_setprio(0);
      // ---- causal mask (diagonal region only) ----
      if (kt >= 2*qt){
        const int kb0 = kt*64 + 4*h;
        #pragma unroll
        for (int r = 0; r < 16; ++r){
          int k0 = kb0 + (r & 3) + 8*(r >> 2);
          if (k0      > myq) s0[r] = -1e30f;
          if (k0 + 32 > myq) s1[r] = -1e30f;
        }
      }
      // ---- row max: in-lane tree + one xor32 ----
      float ma = -1e30f, mb = -1e30f, mc = -1e30f, md = -1e30f;
      #pragma unroll
      for (int r = 0; r < 16; r += 4){
        ma = fmaxf(ma, fmaxf(s0[r],   s0[r+1]));
        mb = fmaxf(mb, fmaxf(s0[r+2], s0[r+3]));
        mc = fmaxf(mc, fmaxf(s1[r],   s1[r+1]));
        md = fmaxf(md, fmaxf(s1[r+2], s1[r+3]));
      }
      float rmax = fmaxf(fmaxf(ma, mb), fmaxf(mc, md));
      rmax = fmaxf(rmax, __shfl_xor(rmax, 32));
      // ---- defer-max: rescale only when max grows past THR=8 (log2 units) ----
      if (__any(rmax > m_run + 8.f)){
        float mn   = fmaxf(m_run, rmax);
        float corr = exp2f(m_run - mn);   // in-lane: same q for all regs
        m_run = mn;
        l_run *= corr;
        #pragma unroll
        for (int r = 0; r < 16; ++r){ oa0[r] *= corr; oa1[r] *= corr; }
      }
      // ---- P = exp2(S-m): pack quads; rowsum in-lane + one xor32 ----
      unsigned w0q[8], w1q[8];
      float rsa = 0.f, rsb = 0.f;
      #pragma unroll
      for (int m = 0; m < 4; ++m){
        float a0 = exp2f(s0[4*m]   - m_run), a1 = exp2f(s0[4*m+1] - m_run);
        float a2 = exp2f(s0[4*m+2] - m_run), a3 = exp2f(s0[4*m+3] - m_run);
        float b0 = exp2f(s1[4*m]   - m_run), b1 = exp2f(s1[4*m+1] - m_run);
        float b2 = exp2f(s1[4*m+2] - m_run), b3 = exp2f(s1[4*m+3] - m_run);
        rsa += (a0 + a1) + (a2 + a3);
        rsb += (b0 + b1) + (b2 + b3);
        w0q[2*m] = pk2(a0, a1); w0q[2*m+1] = pk2(a2, a3);
        w1q[2*m] = pk2(b0, b1); w1q[2*m+1] = pk2(b2, b3);
      }
      float rsum = rsa + rsb;
      rsum += __shfl_xor(rsum, 32);
      l_run += rsum;
      // ---- P^T -> B-frags: 2 permlane32_swap per chunk (lane&31 preserved) ----
      short8 pa[4];
      #pragma unroll
      for (int cc = 0; cc < 2; ++cc){
        {
          unsigned x0 = w0q[4*cc], x1 = w0q[4*cc+1], y0 = w0q[4*cc+2], y1 = w0q[4*cc+3];
          asm("v_permlane32_swap_b32 %0, %1" : "+v"(x0), "+v"(y0));
          asm("v_permlane32_swap_b32 %0, %1" : "+v"(x1), "+v"(y1));
          union { unsigned u[4]; short8 v; } t; t.u[0]=x0; t.u[1]=x1; t.u[2]=y0; t.u[3]=y1;
          pa[cc] = t.v;
        }
        {
          unsigned x0 = w1q[4*cc], x1 = w1q[4*cc+1], y0 = w1q[4*cc+2], y1 = w1q[4*cc+3];
          asm("v_permlane32_swap_b32 %0, %1" : "+v"(x0), "+v"(y0));
          asm("v_permlane32_swap_b32 %0, %1" : "+v"(x1), "+v"(y1));
          union { unsigned u[4]; short8 v; } t; t.u[0]=x0; t.u[1]=x1; t.u[2]=y0; t.u[3]=y1;
          pa[2+cc] = t.v;
        }
      }
      // ---- O^T += V^T P^T: A = V^T rows d, B = pa (k x q) ----
      __builtin_amdgcn_s_setprio(1);
      #pragma unroll
      for (int c = 0; c < 4; ++c){
        const int ch = ((2*c + h) ^ swr) << 3;
        short8 vf0 = *(const short8*)(Vc + (l31     )*64 + ch);
        short8 vf1 = *(const short8*)(Vc + (l31 + 32)*64 + ch);
        oa0 = __builtin_amdgcn_mfma_f32_32x32x16_bf16(vf0, pa[c], oa0, 0, 0, 0);
        oa1 = __builtin_amdgcn_mfma_f32_32x32x16_bf16(vf1, pa[c], oa1, 0, 0, 0);
      }
      __builtin_amdgcn_s_setprio(0);
    }
    __builtin_amdgcn_s_barrier();   // all waves done reading buf before re-stage
  }
#undef A_STAGE
  // ---- normalize (in-lane) + write [B,T,H*hd] bf16, 8B packed stores ----
  const int b = bh >> 4, hh = bh & 15;
  const float rl = 1.0f / l_run;
  unsigned short* aop = ao + (size_t)(b*2048 + myq)*1024 + hh*64;
  #pragma unroll
  for (int rg = 0; rg < 4; ++rg){
    const int d0 = 8*rg + 4*h;
    unsigned long long p0 = 0, p1 = 0;
    #pragma unroll
    for (int j = 0; j < 4; ++j){
      p0 |= (unsigned long long)f2brn(oa0[4*rg + j] * rl) << (16*j);
      p1 |= (unsigned long long)f2brn(oa1[4*rg + j] * rl) << (16*j);
    }
    *(unsigned long long*)(aop + d0)      = p0;
    *(unsigned long long*)(aop + 32 + d0) = p1;
  }
}

extern "C" void kernel_launch(void* const* d_in, const int* in_sizes, int n_in,
                              void* d_out, int out_size, void* d_ws, size_t ws_size,
                              hipStream_t stream){
  const float* x     = (const float*)d_in[0];
  const float* Wqkv  = (const float*)d_in[1];
  const float* bqkv  = (const float*)d_in[2];
  const float* Wproj = (const float*)d_in[3];
  const float* bproj = (const float*)d_in[4];
  float* out = (float*)d_out;

  unsigned short* ws     = (unsigned short*)d_ws;
  unsigned short* xb     = ws;                       // 8192*1024
  unsigned short* wqkvT  = xb + 8388608;             // 3072*1024
  unsigned short* wprojT = wqkvT + 3145728;          // 1024*1024
  unsigned short* qbuf   = wprojT + 1048576;         // [B,H,T,64]
  unsigned short* kbuf   = qbuf + 8388608;
  unsigned short* vbuf   = kbuf + 8388608;           // [B,H,64,T] (transposed)
  unsigned short* ao     = vbuf + 8388608;           // [B,T,1024]

  k_cast_x<<<8192, 256, 0, stream>>>(x, xb, 2097152);
  k_transpose_cast<<<dim3(96, 32), dim3(32, 8), 0, stream>>>(Wqkv, wqkvT, 1024, 3072);
  k_transpose_cast<<<dim3(32, 32), dim3(32, 8), 0, stream>>>(Wproj, wprojT, 1024, 1024);
  k_gemm_bt<0><<<dim3(24, 64), 256, 0, stream>>>(xb, wqkvT, bqkv, nullptr,
                                                 qbuf, kbuf, vbuf, 8192, 3072, 1024);
  k_attn<<<dim3(16, 64), 256, 0, stream>>>(qbuf, kbuf, vbuf, ao);
  k_gemm_bt<1><<<dim3(8, 64), 256, 0, stream>>>(ao, wprojT, bproj, out,
                                                nullptr, nullptr, nullptr, 8192, 1024, 1024);
}